// Round 1
// baseline (7600.632 us; speedup 1.0000x reference)
//
#include <hip/hip_runtime.h>
#include <math.h>

namespace {

constexpr int NL = 4;      // layers
constexpr int DM = 256;    // d_model
constexpr int DI = 512;    // d_inner
constexpr int DS = 16;     // d_state
constexpr int DR = 16;     // dt_rank
constexpr int NF = 32;     // n_features
constexpr int NB = 8;      // batch
constexpr int T  = 2048;   // seq
constexpr int ROWS = NB * T;       // 16384
constexpr int XD = DR + 2 * DS;    // 48

__device__ __forceinline__ float siluf(float x) { return x / (1.f + expf(-x)); }
__device__ __forceinline__ float softplusf(float x) {
    return fmaxf(x, 0.f) + log1pf(expf(-fabsf(x)));
}

// ---------------------------------------------------------------------------
// Generic 16x16-tiled fp32 GEMM.  C[M,N] (op)= A[M,K] @ B[K,N]
// MODE 0: C = A@B (+bias if non-null)
// MODE 1: C += A@B
// MODE 2: split write: col < DI -> C[row*DI+col], else C1[row*DI+col-DI]
// MODE 3: C = softplus(A@B + bias)
// All of M,N,K are multiples of 16 here; no bounds checks.
// ---------------------------------------------------------------------------
template <int MODE>
__global__ void gemm16(const float* __restrict__ A, const float* __restrict__ B,
                       float* __restrict__ C, float* __restrict__ C1,
                       const float* __restrict__ bias,
                       int M, int N, int K, int lda, int ldb, int ldc)
{
    __shared__ float As[16][17];
    __shared__ float Bs[16][17];
    const int tx = threadIdx.x, ty = threadIdx.y;
    const int row = blockIdx.y * 16 + ty;
    const int col = blockIdx.x * 16 + tx;
    float acc = 0.f;
    for (int k0 = 0; k0 < K; k0 += 16) {
        As[ty][tx] = A[row * lda + k0 + tx];
        Bs[ty][tx] = B[(k0 + ty) * ldb + col];
        __syncthreads();
#pragma unroll
        for (int kk = 0; kk < 16; ++kk) acc += As[ty][kk] * Bs[kk][tx];
        __syncthreads();
    }
    if (MODE == 0) {
        if (bias) acc += bias[col];
        C[row * ldc + col] = acc;
    } else if (MODE == 1) {
        C[row * ldc + col] += acc;
    } else if (MODE == 2) {
        if (col < DI) C[row * DI + col] = acc;
        else          C1[row * DI + col - DI] = acc;
    } else { // MODE 3
        C[row * ldc + col] = softplusf(acc + bias[col]);
    }
}

// ---------------------------------------------------------------------------
// LayerNorm over last dim (256), one block of 256 threads per row.
// ---------------------------------------------------------------------------
__global__ void layernorm_kernel(const float* __restrict__ x,
                                 const float* __restrict__ w,
                                 const float* __restrict__ b,
                                 float* __restrict__ out)
{
    const int row = blockIdx.x;
    const int t = threadIdx.x;
    const int wid = t >> 6, lane = t & 63;
    __shared__ float red[4];

    float v = x[row * DM + t];
    float s = v;
#pragma unroll
    for (int o = 32; o >= 1; o >>= 1) s += __shfl_xor(s, o);
    if (lane == 0) red[wid] = s;
    __syncthreads();
    float mu = (red[0] + red[1] + red[2] + red[3]) * (1.f / DM);
    __syncthreads();

    float d = v - mu;
    float q = d * d;
#pragma unroll
    for (int o = 32; o >= 1; o >>= 1) q += __shfl_xor(q, o);
    if (lane == 0) red[wid] = q;
    __syncthreads();
    float var = (red[0] + red[1] + red[2] + red[3]) * (1.f / DM);

    out[row * DM + t] = d * (1.f / sqrtf(var + 1e-5f)) * w[t] + b[t];
}

// ---------------------------------------------------------------------------
// Depthwise causal conv (width 4) + bias + SiLU.  xs: [B*T, DI] -> xc.
// ---------------------------------------------------------------------------
__global__ void conv_silu_kernel(const float* __restrict__ xs,
                                 const float* __restrict__ W,   // [4, DI]
                                 const float* __restrict__ Bc,  // [DI]
                                 float* __restrict__ xc)
{
    const int idx = blockIdx.x * blockDim.x + threadIdx.x; // over ROWS*DI
    const int c = idx & (DI - 1);
    const int bt = idx >> 9;
    const int t = bt & (T - 1);
    float acc = Bc[c];
#pragma unroll
    for (int k = 0; k < 4; ++k) {
        int tt = t + k - 3;
        if (tt >= 0) acc += xs[(bt + k - 3) * DI + c] * W[k * DI + c];
    }
    xc[idx] = siluf(acc);
}

// ---------------------------------------------------------------------------
// Selective scan.  One thread per (b, d, s); 16 lanes (s) reduce via shfl.
// h[b,d,s] <- exp(dt*A[d,s])*h + dt*Bm[b,t,s]*xc[b,t,d];  y = sum_s h*Cm + xc*D
// ---------------------------------------------------------------------------
__global__ void scan_kernel(const float* __restrict__ xd,   // [ROWS, 48]
                            const float* __restrict__ dt,   // [ROWS, DI]
                            const float* __restrict__ xc,   // [ROWS, DI]
                            const float* __restrict__ A_log,// [DI, DS]
                            const float* __restrict__ Dv,   // [DI]
                            float* __restrict__ y)          // [ROWS, DI]
{
    const int tid = blockIdx.x * blockDim.x + threadIdx.x; // NB*DI*DS = 65536
    const int s = tid & 15;
    const int d = (tid >> 4) & (DI - 1);
    const int b = tid >> 13;
    const float A = -expf(A_log[d * DS + s]);
    const float Dd = Dv[d];
    float h = 0.f;
    const int base = b * T;
    for (int t = 0; t < T; ++t) {
        const int row = base + t;
        float dtv = dt[row * DI + d];
        float xcv = xc[row * DI + d];
        float Bm = xd[row * XD + DR + s];
        float Cm = xd[row * XD + DR + DS + s];
        h = expf(dtv * A) * h + dtv * Bm * xcv;
        float p = h * Cm;
        p += __shfl_xor(p, 1);
        p += __shfl_xor(p, 2);
        p += __shfl_xor(p, 4);
        p += __shfl_xor(p, 8);
        if (s == 0) y[row * DI + d] = p + xcv * Dd;
    }
}

// ---------------------------------------------------------------------------
// y *= silu(z), elementwise.
// ---------------------------------------------------------------------------
__global__ void gate_kernel(float* __restrict__ y, const float* __restrict__ z)
{
    const int idx = blockIdx.x * blockDim.x + threadIdx.x;
    y[idx] *= siluf(z[idx]);
}

// ---------------------------------------------------------------------------
// Head: final LN on last token, gelu(last@h1W+h1b) @ h2W + h2b.
// One block (256 threads) per batch element.
// ---------------------------------------------------------------------------
__global__ void head_kernel(const float* __restrict__ h,
                            const float* __restrict__ fw, const float* __restrict__ fb,
                            const float* __restrict__ h1W, const float* __restrict__ h1b,
                            const float* __restrict__ h2W, const float* __restrict__ h2b,
                            float* __restrict__ out)
{
    const int bi = blockIdx.x;
    const int t = threadIdx.x;
    const int wid = t >> 6, lane = t & 63;
    __shared__ float red[4];
    __shared__ float ln[DM];
    __shared__ float hid[DM / 2];

    const float* row = h + ((bi + 1) * T - 1) * DM;
    float v = row[t];
    float s = v;
#pragma unroll
    for (int o = 32; o >= 1; o >>= 1) s += __shfl_xor(s, o);
    if (lane == 0) red[wid] = s;
    __syncthreads();
    float mu = (red[0] + red[1] + red[2] + red[3]) * (1.f / DM);
    __syncthreads();
    float d = v - mu;
    float q = d * d;
#pragma unroll
    for (int o = 32; o >= 1; o >>= 1) q += __shfl_xor(q, o);
    if (lane == 0) red[wid] = q;
    __syncthreads();
    float var = (red[0] + red[1] + red[2] + red[3]) * (1.f / DM);
    ln[t] = d * (1.f / sqrtf(var + 1e-5f)) * fw[t] + fb[t];
    __syncthreads();

    if (t < DM / 2) {
        float acc = h1b[t];
        for (int k = 0; k < DM; ++k) acc += ln[k] * h1W[k * (DM / 2) + t];
        // tanh-approx GELU (JAX default approximate=True)
        float x3 = acc * acc * acc;
        hid[t] = 0.5f * acc * (1.f + tanhf(0.7978845608028654f * (acc + 0.044715f * x3)));
    }
    __syncthreads();
    if (t < 3) {
        float acc = h2b[t];
        for (int k = 0; k < DM / 2; ++k) acc += hid[k] * h2W[k * 3 + t];
        out[bi * 3 + t] = acc;
    }
}

} // namespace

extern "C" void kernel_launch(void* const* d_in, const int* in_sizes, int n_in,
                              void* d_out, int out_size, void* d_ws, size_t ws_size,
                              hipStream_t stream)
{
    (void)in_sizes; (void)n_in; (void)out_size; (void)ws_size;
    const float* x     = (const float*)d_in[0];
    const float* in_w  = (const float*)d_in[1];
    const float* in_b  = (const float*)d_in[2];
    const float* ln_w  = (const float*)d_in[3];
    const float* ln_b  = (const float*)d_in[4];
    const float* inW   = (const float*)d_in[5];
    const float* convW = (const float*)d_in[6];
    const float* convB = (const float*)d_in[7];
    const float* xpW   = (const float*)d_in[8];
    const float* dtW   = (const float*)d_in[9];
    const float* A_log = (const float*)d_in[10];
    const float* Dv    = (const float*)d_in[11];
    const float* outW  = (const float*)d_in[12];
    const float* fln_w = (const float*)d_in[13];
    const float* fln_b = (const float*)d_in[14];
    const float* h1W   = (const float*)d_in[15];
    const float* h1b   = (const float*)d_in[16];
    const float* h2W   = (const float*)d_in[17];
    const float* h2b   = (const float*)d_in[18];
    const float* dtB   = (const float*)d_in[19];
    float* out = (float*)d_out;

    float* w = (float*)d_ws;
    float* hbuf = w;  w += ROWS * DM;   // residual stream
    float* xln  = w;  w += ROWS * DM;
    float* xs   = w;  w += ROWS * DI;
    float* z    = w;  w += ROWS * DI;
    float* xc   = w;  w += ROWS * DI;
    float* dt   = w;  w += ROWS * DI;
    float* xd   = w;  w += ROWS * XD;
    float* y = xs;    // xs is dead after the conv; reuse for y

    dim3 blk(16, 16);

    // h = x @ in_w + in_b
    gemm16<0><<<dim3(DM / 16, ROWS / 16), blk, 0, stream>>>(
        x, in_w, hbuf, nullptr, in_b, ROWS, DM, NF, NF, DM, DM);

    for (int i = 0; i < NL; ++i) {
        layernorm_kernel<<<ROWS, DM, 0, stream>>>(hbuf, ln_w + i * DM, ln_b + i * DM, xln);

        // xz = xln @ inW[i]   -> split xs | z
        gemm16<2><<<dim3(2 * DI / 16, ROWS / 16), blk, 0, stream>>>(
            xln, inW + i * DM * 2 * DI, xs, z, nullptr, ROWS, 2 * DI, DM, DM, 2 * DI, 0);

        conv_silu_kernel<<<ROWS * DI / 256, 256, 0, stream>>>(
            xs, convW + i * 4 * DI, convB + i * DI, xc);

        // xd = xc @ xpW[i]
        gemm16<0><<<dim3(XD / 16, ROWS / 16), blk, 0, stream>>>(
            xc, xpW + i * DI * XD, xd, nullptr, nullptr, ROWS, XD, DI, DI, XD, XD);

        // dt = softplus(xd[:, :16] @ dtW[i] + dtB[i])
        gemm16<3><<<dim3(DI / 16, ROWS / 16), blk, 0, stream>>>(
            xd, dtW + i * DR * DI, dt, nullptr, dtB + i * DI, ROWS, DI, DR, XD, DI, DI);

        scan_kernel<<<NB * DI * DS / 256, 256, 0, stream>>>(
            xd, dt, xc, A_log + i * DI * DS, Dv + i * DI, y);

        gate_kernel<<<ROWS * DI / 256, 256, 0, stream>>>(y, z);

        // h += y @ outW[i]
        gemm16<1><<<dim3(DM / 16, ROWS / 16), blk, 0, stream>>>(
            y, outW + i * DI * DM, hbuf, nullptr, nullptr, ROWS, DM, DI, DI, DM, DM);
    }

    head_kernel<<<NB, DM, 0, stream>>>(hbuf, fln_w, fln_b, h1W, h1b, h2W, h2b, out);
}

// Round 2
// 4914.602 us; speedup vs baseline: 1.5465x; 1.5465x over previous
//
#include <hip/hip_runtime.h>
#include <math.h>

namespace {

constexpr int NL = 4;      // layers
constexpr int DM = 256;    // d_model
constexpr int DI = 512;    // d_inner
constexpr int DS = 16;     // d_state
constexpr int DR = 16;     // dt_rank
constexpr int NF = 32;     // n_features
constexpr int NB = 8;      // batch
constexpr int T  = 2048;   // seq
constexpr int ROWS = NB * T;       // 16384
constexpr int XD = DR + 2 * DS;    // 48
constexpr int NC = 64;             // scan chunks
constexpr int CL = T / NC;         // 32 steps per chunk
constexpr int SCN = NB * DI * DS;  // 65536 scan lanes

__device__ __forceinline__ float siluf(float x) { return x / (1.f + expf(-x)); }
__device__ __forceinline__ float softplusf(float x) {
    return fmaxf(x, 0.f) + log1pf(expf(-fabsf(x)));
}

// ---------------------------------------------------------------------------
// Generic 16x16-tiled fp32 GEMM.  C[M,N] (op)= A[M,K] @ B[K,N]
// MODE 0: C = A@B (+bias if non-null)
// MODE 1: C += A@B
// MODE 2: split write: col < DI -> C[row*DI+col], else C1[row*DI+col-DI]
// MODE 3: C = softplus(A@B + bias)
// ---------------------------------------------------------------------------
template <int MODE>
__global__ void gemm16(const float* __restrict__ A, const float* __restrict__ B,
                       float* __restrict__ C, float* __restrict__ C1,
                       const float* __restrict__ bias,
                       int M, int N, int K, int lda, int ldb, int ldc)
{
    __shared__ float As[16][17];
    __shared__ float Bs[16][17];
    const int tx = threadIdx.x, ty = threadIdx.y;
    const int row = blockIdx.y * 16 + ty;
    const int col = blockIdx.x * 16 + tx;
    float acc = 0.f;
    for (int k0 = 0; k0 < K; k0 += 16) {
        As[ty][tx] = A[row * lda + k0 + tx];
        Bs[ty][tx] = B[(k0 + ty) * ldb + col];
        __syncthreads();
#pragma unroll
        for (int kk = 0; kk < 16; ++kk) acc += As[ty][kk] * Bs[kk][tx];
        __syncthreads();
    }
    if (MODE == 0) {
        if (bias) acc += bias[col];
        C[row * ldc + col] = acc;
    } else if (MODE == 1) {
        C[row * ldc + col] += acc;
    } else if (MODE == 2) {
        if (col < DI) C[row * DI + col] = acc;
        else          C1[row * DI + col - DI] = acc;
    } else { // MODE 3
        C[row * ldc + col] = softplusf(acc + bias[col]);
    }
}

// ---------------------------------------------------------------------------
// LayerNorm over last dim (256), one block of 256 threads per row.
// ---------------------------------------------------------------------------
__global__ void layernorm_kernel(const float* __restrict__ x,
                                 const float* __restrict__ w,
                                 const float* __restrict__ b,
                                 float* __restrict__ out)
{
    const int row = blockIdx.x;
    const int t = threadIdx.x;
    const int wid = t >> 6, lane = t & 63;
    __shared__ float red[4];

    float v = x[row * DM + t];
    float s = v;
#pragma unroll
    for (int o = 32; o >= 1; o >>= 1) s += __shfl_xor(s, o);
    if (lane == 0) red[wid] = s;
    __syncthreads();
    float mu = (red[0] + red[1] + red[2] + red[3]) * (1.f / DM);
    __syncthreads();

    float d = v - mu;
    float q = d * d;
#pragma unroll
    for (int o = 32; o >= 1; o >>= 1) q += __shfl_xor(q, o);
    if (lane == 0) red[wid] = q;
    __syncthreads();
    float var = (red[0] + red[1] + red[2] + red[3]) * (1.f / DM);

    out[row * DM + t] = d * (1.f / sqrtf(var + 1e-5f)) * w[t] + b[t];
}

// ---------------------------------------------------------------------------
// Depthwise causal conv (width 4) + bias + SiLU.  xs: [B*T, DI] -> xc.
// ---------------------------------------------------------------------------
__global__ void conv_silu_kernel(const float* __restrict__ xs,
                                 const float* __restrict__ W,   // [4, DI]
                                 const float* __restrict__ Bc,  // [DI]
                                 float* __restrict__ xc)
{
    const int idx = blockIdx.x * blockDim.x + threadIdx.x; // over ROWS*DI
    const int c = idx & (DI - 1);
    const int bt = idx >> 9;
    const int t = bt & (T - 1);
    float acc = Bc[c];
#pragma unroll
    for (int k = 0; k < 4; ++k) {
        int tt = t + k - 3;
        if (tt >= 0) acc += xs[(bt + k - 3) * DI + c] * W[k * DI + c];
    }
    xc[idx] = siluf(acc);
}

// ---------------------------------------------------------------------------
// Chunked selective scan, pass 1: per (b,d,s,chunk) compute the chunk's
// decay product P and local end-state S (h0 = 0).
// Thread map: threadIdx.x = dlo*16 + s (16 d x 16 s per block).
// ---------------------------------------------------------------------------
__global__ void scan_pass1(const float* __restrict__ xd,   // [ROWS, 48]
                           const float* __restrict__ dt,   // [ROWS, DI]
                           const float* __restrict__ xc,   // [ROWS, DI]
                           const float* __restrict__ A_log,// [DI, DS]
                           float* __restrict__ P,          // [NC, SCN]
                           float* __restrict__ S)          // [NC, SCN]
{
    const int s   = threadIdx.x & 15;
    const int dlo = threadIdx.x >> 4;          // 0..15
    const int dblk = blockIdx.x & 31;          // DI/16
    const int c    = (blockIdx.x >> 5) & (NC - 1);
    const int b    = blockIdx.x >> 11;
    const int d = dblk * 16 + dlo;

    const float A = -expf(A_log[d * DS + s]);
    float p = 1.f, sacc = 0.f;
    const int row0 = b * T + c * CL;
#pragma unroll 4
    for (int t = 0; t < CL; ++t) {
        const int row = row0 + t;
        float dtv = dt[row * DI + d];
        float xcv = xc[row * DI + d];
        float Bm  = xd[row * XD + DR + s];
        float a = expf(dtv * A);
        sacc = a * sacc + dtv * Bm * xcv;
        p *= a;
    }
    const int idx3 = (b * DI + d) * DS + s;
    P[c * SCN + idx3] = p;
    S[c * SCN + idx3] = sacc;
}

// ---------------------------------------------------------------------------
// Chunk combine: H_c = state at chunk start.  Overwrites P with H in place.
// ---------------------------------------------------------------------------
__global__ void scan_combine(float* __restrict__ P, const float* __restrict__ S)
{
    const int idx3 = blockIdx.x * blockDim.x + threadIdx.x; // SCN threads
    float h = 0.f;
    for (int c = 0; c < NC; ++c) {
        float pc = P[c * SCN + idx3];
        float sc = S[c * SCN + idx3];
        P[c * SCN + idx3] = h;   // state entering chunk c
        h = pc * h + sc;
    }
}

// ---------------------------------------------------------------------------
// Pass 2: re-run local scan seeded with H, reduce over s (16-lane shfl),
// add the D skip term and apply the silu(z) gate.  Writes gated y.
// ---------------------------------------------------------------------------
__global__ void scan_pass2(const float* __restrict__ xd,
                           const float* __restrict__ dt,
                           const float* __restrict__ xc,
                           const float* __restrict__ A_log,
                           const float* __restrict__ Dv,   // [DI]
                           const float* __restrict__ H,    // [NC, SCN] (=P)
                           const float* __restrict__ z,    // [ROWS, DI]
                           float* __restrict__ y)          // [ROWS, DI]
{
    const int s   = threadIdx.x & 15;
    const int dlo = threadIdx.x >> 4;
    const int dblk = blockIdx.x & 31;
    const int c    = (blockIdx.x >> 5) & (NC - 1);
    const int b    = blockIdx.x >> 11;
    const int d = dblk * 16 + dlo;

    const float A  = -expf(A_log[d * DS + s]);
    const float Dd = Dv[d];
    const int idx3 = (b * DI + d) * DS + s;
    float h = H[c * SCN + idx3];
    const int row0 = b * T + c * CL;
#pragma unroll 4
    for (int t = 0; t < CL; ++t) {
        const int row = row0 + t;
        float dtv = dt[row * DI + d];
        float xcv = xc[row * DI + d];
        float Bm  = xd[row * XD + DR + s];
        float Cm  = xd[row * XD + DR + DS + s];
        float a = expf(dtv * A);
        h = a * h + dtv * Bm * xcv;
        float pv = h * Cm;
        pv += __shfl_xor(pv, 1);
        pv += __shfl_xor(pv, 2);
        pv += __shfl_xor(pv, 4);
        pv += __shfl_xor(pv, 8);
        if (s == 0) {
            float zv = z[row * DI + d];
            y[row * DI + d] = (pv + xcv * Dd) * siluf(zv);
        }
    }
}

// ---------------------------------------------------------------------------
// Head: final LN on last token, gelu(last@h1W+h1b) @ h2W + h2b.
// ---------------------------------------------------------------------------
__global__ void head_kernel(const float* __restrict__ h,
                            const float* __restrict__ fw, const float* __restrict__ fb,
                            const float* __restrict__ h1W, const float* __restrict__ h1b,
                            const float* __restrict__ h2W, const float* __restrict__ h2b,
                            float* __restrict__ out)
{
    const int bi = blockIdx.x;
    const int t = threadIdx.x;
    const int wid = t >> 6, lane = t & 63;
    __shared__ float red[4];
    __shared__ float ln[DM];
    __shared__ float hid[DM / 2];

    const float* row = h + ((bi + 1) * T - 1) * DM;
    float v = row[t];
    float s = v;
#pragma unroll
    for (int o = 32; o >= 1; o >>= 1) s += __shfl_xor(s, o);
    if (lane == 0) red[wid] = s;
    __syncthreads();
    float mu = (red[0] + red[1] + red[2] + red[3]) * (1.f / DM);
    __syncthreads();
    float d = v - mu;
    float q = d * d;
#pragma unroll
    for (int o = 32; o >= 1; o >>= 1) q += __shfl_xor(q, o);
    if (lane == 0) red[wid] = q;
    __syncthreads();
    float var = (red[0] + red[1] + red[2] + red[3]) * (1.f / DM);
    ln[t] = d * (1.f / sqrtf(var + 1e-5f)) * fw[t] + fb[t];
    __syncthreads();

    if (t < DM / 2) {
        float acc = h1b[t];
        for (int k = 0; k < DM; ++k) acc += ln[k] * h1W[k * (DM / 2) + t];
        float x3 = acc * acc * acc;
        hid[t] = 0.5f * acc * (1.f + tanhf(0.7978845608028654f * (acc + 0.044715f * x3)));
    }
    __syncthreads();
    if (t < 3) {
        float acc = h2b[t];
        for (int k = 0; k < DM / 2; ++k) acc += hid[k] * h2W[k * 3 + t];
        out[bi * 3 + t] = acc;
    }
}

} // namespace

extern "C" void kernel_launch(void* const* d_in, const int* in_sizes, int n_in,
                              void* d_out, int out_size, void* d_ws, size_t ws_size,
                              hipStream_t stream)
{
    (void)in_sizes; (void)n_in; (void)out_size; (void)ws_size;
    const float* x     = (const float*)d_in[0];
    const float* in_w  = (const float*)d_in[1];
    const float* in_b  = (const float*)d_in[2];
    const float* ln_w  = (const float*)d_in[3];
    const float* ln_b  = (const float*)d_in[4];
    const float* inW   = (const float*)d_in[5];
    const float* convW = (const float*)d_in[6];
    const float* convB = (const float*)d_in[7];
    const float* xpW   = (const float*)d_in[8];
    const float* dtW   = (const float*)d_in[9];
    const float* A_log = (const float*)d_in[10];
    const float* Dv    = (const float*)d_in[11];
    const float* outW  = (const float*)d_in[12];
    const float* fln_w = (const float*)d_in[13];
    const float* fln_b = (const float*)d_in[14];
    const float* h1W   = (const float*)d_in[15];
    const float* h1b   = (const float*)d_in[16];
    const float* h2W   = (const float*)d_in[17];
    const float* h2b   = (const float*)d_in[18];
    const float* dtB   = (const float*)d_in[19];
    float* out = (float*)d_out;

    float* w = (float*)d_ws;
    float* hbuf = w;  w += ROWS * DM;   // residual stream
    float* xln  = w;  w += ROWS * DM;   // LN output; later aliased as S
    float* xs   = w;  w += ROWS * DI;
    float* z    = w;  w += ROWS * DI;
    float* xc   = w;  w += ROWS * DI;
    float* dt   = w;  w += ROWS * DI;
    float* xd   = w;  w += ROWS * XD;
    float* P    = w;  w += SCN * NC;    // chunk decay products / start states
    float* y = xs;    // xs dead after conv
    float* S = xln;   // xln dead after in-proj GEMM; same size (4.19M floats)

    dim3 blk(16, 16);

    // h = x @ in_w + in_b
    gemm16<0><<<dim3(DM / 16, ROWS / 16), blk, 0, stream>>>(
        x, in_w, hbuf, nullptr, in_b, ROWS, DM, NF, NF, DM, DM);

    for (int i = 0; i < NL; ++i) {
        layernorm_kernel<<<ROWS, DM, 0, stream>>>(hbuf, ln_w + i * DM, ln_b + i * DM, xln);

        // xz = xln @ inW[i]   -> split xs | z
        gemm16<2><<<dim3(2 * DI / 16, ROWS / 16), blk, 0, stream>>>(
            xln, inW + i * DM * 2 * DI, xs, z, nullptr, ROWS, 2 * DI, DM, DM, 2 * DI, 0);

        conv_silu_kernel<<<ROWS * DI / 256, 256, 0, stream>>>(
            xs, convW + i * 4 * DI, convB + i * DI, xc);

        // xd = xc @ xpW[i]
        gemm16<0><<<dim3(XD / 16, ROWS / 16), blk, 0, stream>>>(
            xc, xpW + i * DI * XD, xd, nullptr, nullptr, ROWS, XD, DI, DI, XD, XD);

        // dt = softplus(xd[:, :16] @ dtW[i] + dtB[i])
        gemm16<3><<<dim3(DI / 16, ROWS / 16), blk, 0, stream>>>(
            xd, dtW + i * DR * DI, dt, nullptr, dtB + i * DI, ROWS, DI, DR, XD, DI, DI);

        // chunked scan: pass1 -> combine -> pass2 (+ fused gate)
        scan_pass1<<<NB * NC * (DI / 16), 256, 0, stream>>>(
            xd, dt, xc, A_log + i * DI * DS, P, S);
        scan_combine<<<SCN / 256, 256, 0, stream>>>(P, S);
        scan_pass2<<<NB * NC * (DI / 16), 256, 0, stream>>>(
            xd, dt, xc, A_log + i * DI * DS, Dv + i * DI, P, z, y);

        // h += y @ outW[i]
        gemm16<1><<<dim3(DM / 16, ROWS / 16), blk, 0, stream>>>(
            y, outW + i * DI * DM, hbuf, nullptr, nullptr, ROWS, DM, DI, DI, DM, DM);
    }

    head_kernel<<<NB, DM, 0, stream>>>(hbuf, fln_w, fln_b, h1W, h1b, h2W, h2b, out);
}

// Round 3
// 2069.759 us; speedup vs baseline: 3.6722x; 2.3745x over previous
//
#include <hip/hip_runtime.h>
#include <math.h>

namespace {

constexpr int NL = 4;      // layers
constexpr int DM = 256;    // d_model
constexpr int DI = 512;    // d_inner
constexpr int DS = 16;     // d_state
constexpr int DR = 16;     // dt_rank
constexpr int NF = 32;     // n_features
constexpr int NB = 8;      // batch
constexpr int T  = 2048;   // seq
constexpr int ROWS = NB * T;       // 16384
constexpr int XD = DR + 2 * DS;    // 48
constexpr int NC = 64;             // scan chunks
constexpr int CL = T / NC;         // 32 steps per chunk
constexpr int SCN = NB * DI * DS;  // 65536 scan lanes

typedef __attribute__((ext_vector_type(4))) float f32x4;
typedef __attribute__((ext_vector_type(8))) short bf16x8;
typedef __attribute__((ext_vector_type(4))) short bf16x4;

__device__ __forceinline__ float siluf(float x) { return x / (1.f + expf(-x)); }
__device__ __forceinline__ float softplusf(float x) {
    return fmaxf(x, 0.f) + log1pf(expf(-fabsf(x)));
}
__device__ __forceinline__ short f2bf(float f) {   // RNE float->bf16
    union { float f; unsigned u; } c; c.f = f;
    unsigned r = (c.u + 0x7FFFu + ((c.u >> 16) & 1u)) >> 16;
    return (short)r;
}

// ---------------------------------------------------------------------------
// fp32 16x16 GEMM — kept only for the tiny first projection (K=32).
// ---------------------------------------------------------------------------
__global__ void gemm16(const float* __restrict__ A, const float* __restrict__ B,
                       float* __restrict__ C, const float* __restrict__ bias,
                       int M, int N, int K, int lda, int ldb, int ldc)
{
    __shared__ float As[16][17];
    __shared__ float Bs[16][17];
    const int tx = threadIdx.x, ty = threadIdx.y;
    const int row = blockIdx.y * 16 + ty;
    const int col = blockIdx.x * 16 + tx;
    float acc = 0.f;
    for (int k0 = 0; k0 < K; k0 += 16) {
        As[ty][tx] = A[row * lda + k0 + tx];
        Bs[ty][tx] = B[(k0 + ty) * ldb + col];
        __syncthreads();
#pragma unroll
        for (int kk = 0; kk < 16; ++kk) acc += As[ty][kk] * Bs[kk][tx];
        __syncthreads();
    }
    C[row * ldc + col] = acc + bias[col];
}

// ---------------------------------------------------------------------------
// Weight prep: dst[Npad][K] (bf16) = transpose(src[K][N]), zero-pad n>=N.
// ---------------------------------------------------------------------------
__global__ void wtrans(const float* __restrict__ src, short* __restrict__ dst,
                       int K, int N, int Npad)
{
    const int idx = blockIdx.x * 256 + threadIdx.x;   // over Npad*K
    const unsigned n = (unsigned)idx / (unsigned)K;
    const unsigned k = (unsigned)idx - n * (unsigned)K;
    float v = (n < (unsigned)N) ? src[k * N + n] : 0.f;
    dst[idx] = f2bf(v);
}

// ---------------------------------------------------------------------------
// MFMA bf16 GEMM.  C[M,N] = A[M,K](fp32, rounded to bf16 in staging)
//                          @ B  (passed as Bt[Npad][K] bf16, N-major).
// Tile 128x64, 256 threads = 4 waves (2x2), each wave 64x32 = 4x2 frags of
// v_mfma_f32_16x16x32_bf16.  LDS pitch 40 shorts -> <=2-way bank aliasing.
// EP 0: split write at col 512 -> C | C1 (both [*,512])      [in-proj]
// EP 1: C[row*ldc+col] = acc for col < Ncut                  [x-proj]
// EP 2: C[row*ldc+col] += acc                                [out-proj]
// ---------------------------------------------------------------------------
template <int EP>
__global__ void gemm_mfma(const float* __restrict__ A, const short* __restrict__ Bt,
                          float* __restrict__ C, float* __restrict__ C1,
                          int K, int lda, int ldc, int Ncut)
{
    __shared__ short smem[7680];          // A: 128*40, B: 64*40 (shorts)
    const int tid = threadIdx.x;
    const int lane = tid & 63, w = tid >> 6;
    const int wr = w >> 1, wc = w & 1;
    const int lr = lane & 15, lk = lane >> 4;
    const int m0 = blockIdx.y * 128;
    const int n0 = blockIdx.x * 64;

    f32x4 acc[4][2] = {};
    for (int k0 = 0; k0 < K; k0 += 32) {
        __syncthreads();
        // stage A: 128 rows x 32 k, fp32 -> bf16
#pragma unroll
        for (int i = 0; i < 4; ++i) {
            int c = tid + i * 256;
            int row = c >> 3, kc = c & 7;
            f32x4 v = *(const f32x4*)(A + (size_t)(m0 + row) * lda + k0 + kc * 4);
            bf16x4 o;
            o[0] = f2bf(v[0]); o[1] = f2bf(v[1]); o[2] = f2bf(v[2]); o[3] = f2bf(v[3]);
            *(bf16x4*)(&smem[row * 40 + kc * 4]) = o;
        }
        // stage B: 64 rows x 32 k, bf16 direct
        {
            int row = tid >> 2, kc = tid & 3;
            bf16x8 v = *(const bf16x8*)(Bt + (size_t)(n0 + row) * K + k0 + kc * 8);
            *(bf16x8*)(&smem[5120 + row * 40 + kc * 8]) = v;
        }
        __syncthreads();
        bf16x8 af[4], bfr[2];
#pragma unroll
        for (int m = 0; m < 4; ++m)
            af[m] = *(const bf16x8*)(&smem[(wr * 64 + m * 16 + lr) * 40 + lk * 8]);
#pragma unroll
        for (int n = 0; n < 2; ++n)
            bfr[n] = *(const bf16x8*)(&smem[5120 + (wc * 32 + n * 16 + lr) * 40 + lk * 8]);
#pragma unroll
        for (int m = 0; m < 4; ++m)
#pragma unroll
            for (int n = 0; n < 2; ++n)
                acc[m][n] = __builtin_amdgcn_mfma_f32_16x16x32_bf16(af[m], bfr[n], acc[m][n], 0, 0, 0);
    }
#pragma unroll
    for (int m = 0; m < 4; ++m) {
#pragma unroll
        for (int n = 0; n < 2; ++n) {
            const int col = n0 + wc * 32 + n * 16 + lr;
#pragma unroll
            for (int j = 0; j < 4; ++j) {
                const int row = m0 + wr * 64 + m * 16 + lk * 4 + j;
                const float v = acc[m][n][j];
                if (EP == 0) {
                    if (col < DI) C[(size_t)row * DI + col] = v;
                    else          C1[(size_t)row * DI + col - DI] = v;
                } else if (EP == 1) {
                    if (col < Ncut) C[(size_t)row * ldc + col] = v;
                } else {
                    C[(size_t)row * ldc + col] += v;
                }
            }
        }
    }
}

// ---------------------------------------------------------------------------
// dt = softplus(xd[:, :16] @ dtW + dtB) — exact fp32, K=16 dot per output.
// One block (512 thr) per row; dtW (32 KB) lives in L2.
// ---------------------------------------------------------------------------
__global__ void dt_kernel(const float* __restrict__ xd, const float* __restrict__ dtW,
                          const float* __restrict__ dtB, float* __restrict__ dt)
{
    const int row = blockIdx.x;
    const int d = threadIdx.x;
    __shared__ float xr[DR];
    if (d < DR) xr[d] = xd[row * XD + d];
    __syncthreads();
    float acc = dtB[d];
#pragma unroll
    for (int r = 0; r < DR; ++r) acc += xr[r] * dtW[r * DI + d];
    dt[(size_t)row * DI + d] = softplusf(acc);
}

// ---------------------------------------------------------------------------
// LayerNorm over last dim (256), one block of 256 threads per row.
// ---------------------------------------------------------------------------
__global__ void layernorm_kernel(const float* __restrict__ x,
                                 const float* __restrict__ w,
                                 const float* __restrict__ b,
                                 float* __restrict__ out)
{
    const int row = blockIdx.x;
    const int t = threadIdx.x;
    const int wid = t >> 6, lane = t & 63;
    __shared__ float red[4];

    float v = x[row * DM + t];
    float s = v;
#pragma unroll
    for (int o = 32; o >= 1; o >>= 1) s += __shfl_xor(s, o);
    if (lane == 0) red[wid] = s;
    __syncthreads();
    float mu = (red[0] + red[1] + red[2] + red[3]) * (1.f / DM);
    __syncthreads();

    float d = v - mu;
    float q = d * d;
#pragma unroll
    for (int o = 32; o >= 1; o >>= 1) q += __shfl_xor(q, o);
    if (lane == 0) red[wid] = q;
    __syncthreads();
    float var = (red[0] + red[1] + red[2] + red[3]) * (1.f / DM);

    out[row * DM + t] = d * (1.f / sqrtf(var + 1e-5f)) * w[t] + b[t];
}

// ---------------------------------------------------------------------------
// Depthwise causal conv (width 4) + bias + SiLU.
// ---------------------------------------------------------------------------
__global__ void conv_silu_kernel(const float* __restrict__ xs,
                                 const float* __restrict__ W,   // [4, DI]
                                 const float* __restrict__ Bc,  // [DI]
                                 float* __restrict__ xc)
{
    const int idx = blockIdx.x * blockDim.x + threadIdx.x;
    const int c = idx & (DI - 1);
    const int bt = idx >> 9;
    const int t = bt & (T - 1);
    float acc = Bc[c];
#pragma unroll
    for (int k = 0; k < 4; ++k) {
        int tt = t + k - 3;
        if (tt >= 0) acc += xs[(bt + k - 3) * DI + c] * W[k * DI + c];
    }
    xc[idx] = siluf(acc);
}

// ---------------------------------------------------------------------------
// Chunked selective scan (pass1 / combine / pass2, gate fused in pass2).
// ---------------------------------------------------------------------------
__global__ void scan_pass1(const float* __restrict__ xd,
                           const float* __restrict__ dt,
                           const float* __restrict__ xc,
                           const float* __restrict__ A_log,
                           float* __restrict__ P, float* __restrict__ S)
{
    const int s   = threadIdx.x & 15;
    const int dlo = threadIdx.x >> 4;
    const int dblk = blockIdx.x & 31;
    const int c    = (blockIdx.x >> 5) & (NC - 1);
    const int b    = blockIdx.x >> 11;
    const int d = dblk * 16 + dlo;

    const float A = -expf(A_log[d * DS + s]);
    float p = 1.f, sacc = 0.f;
    const int row0 = b * T + c * CL;
#pragma unroll 4
    for (int t = 0; t < CL; ++t) {
        const int row = row0 + t;
        float dtv = dt[row * DI + d];
        float xcv = xc[row * DI + d];
        float Bm  = xd[row * XD + DR + s];
        float a = expf(dtv * A);
        sacc = a * sacc + dtv * Bm * xcv;
        p *= a;
    }
    const int idx3 = (b * DI + d) * DS + s;
    P[c * SCN + idx3] = p;
    S[c * SCN + idx3] = sacc;
}

__global__ void scan_combine(float* __restrict__ P, const float* __restrict__ S)
{
    const int idx3 = blockIdx.x * blockDim.x + threadIdx.x;
    float h = 0.f;
    for (int c = 0; c < NC; ++c) {
        float pc = P[c * SCN + idx3];
        float sc = S[c * SCN + idx3];
        P[c * SCN + idx3] = h;
        h = pc * h + sc;
    }
}

__global__ void scan_pass2(const float* __restrict__ xd,
                           const float* __restrict__ dt,
                           const float* __restrict__ xc,
                           const float* __restrict__ A_log,
                           const float* __restrict__ Dv,
                           const float* __restrict__ H,
                           const float* __restrict__ z,
                           float* __restrict__ y)
{
    const int s   = threadIdx.x & 15;
    const int dlo = threadIdx.x >> 4;
    const int dblk = blockIdx.x & 31;
    const int c    = (blockIdx.x >> 5) & (NC - 1);
    const int b    = blockIdx.x >> 11;
    const int d = dblk * 16 + dlo;

    const float A  = -expf(A_log[d * DS + s]);
    const float Dd = Dv[d];
    const int idx3 = (b * DI + d) * DS + s;
    float h = H[c * SCN + idx3];
    const int row0 = b * T + c * CL;
#pragma unroll 4
    for (int t = 0; t < CL; ++t) {
        const int row = row0 + t;
        float dtv = dt[row * DI + d];
        float xcv = xc[row * DI + d];
        float Bm  = xd[row * XD + DR + s];
        float Cm  = xd[row * XD + DR + DS + s];
        float a = expf(dtv * A);
        h = a * h + dtv * Bm * xcv;
        float pv = h * Cm;
        pv += __shfl_xor(pv, 1);
        pv += __shfl_xor(pv, 2);
        pv += __shfl_xor(pv, 4);
        pv += __shfl_xor(pv, 8);
        if (s == 0) {
            float zv = z[row * DI + d];
            y[row * DI + d] = (pv + xcv * Dd) * siluf(zv);
        }
    }
}

// ---------------------------------------------------------------------------
// Head: final LN on last token, gelu(last@h1W+h1b) @ h2W + h2b.
// ---------------------------------------------------------------------------
__global__ void head_kernel(const float* __restrict__ h,
                            const float* __restrict__ fw, const float* __restrict__ fb,
                            const float* __restrict__ h1W, const float* __restrict__ h1b,
                            const float* __restrict__ h2W, const float* __restrict__ h2b,
                            float* __restrict__ out)
{
    const int bi = blockIdx.x;
    const int t = threadIdx.x;
    const int wid = t >> 6, lane = t & 63;
    __shared__ float red[4];
    __shared__ float ln[DM];
    __shared__ float hid[DM / 2];

    const float* row = h + ((bi + 1) * T - 1) * DM;
    float v = row[t];
    float s = v;
#pragma unroll
    for (int o = 32; o >= 1; o >>= 1) s += __shfl_xor(s, o);
    if (lane == 0) red[wid] = s;
    __syncthreads();
    float mu = (red[0] + red[1] + red[2] + red[3]) * (1.f / DM);
    __syncthreads();
    float d = v - mu;
    float q = d * d;
#pragma unroll
    for (int o = 32; o >= 1; o >>= 1) q += __shfl_xor(q, o);
    if (lane == 0) red[wid] = q;
    __syncthreads();
    float var = (red[0] + red[1] + red[2] + red[3]) * (1.f / DM);
    ln[t] = d * (1.f / sqrtf(var + 1e-5f)) * fw[t] + fb[t];
    __syncthreads();

    if (t < DM / 2) {
        float acc = h1b[t];
        for (int k = 0; k < DM; ++k) acc += ln[k] * h1W[k * (DM / 2) + t];
        float x3 = acc * acc * acc;
        hid[t] = 0.5f * acc * (1.f + tanhf(0.7978845608028654f * (acc + 0.044715f * x3)));
    }
    __syncthreads();
    if (t < 3) {
        float acc = h2b[t];
        for (int k = 0; k < DM / 2; ++k) acc += hid[k] * h2W[k * 3 + t];
        out[bi * 3 + t] = acc;
    }
}

} // namespace

extern "C" void kernel_launch(void* const* d_in, const int* in_sizes, int n_in,
                              void* d_out, int out_size, void* d_ws, size_t ws_size,
                              hipStream_t stream)
{
    (void)in_sizes; (void)n_in; (void)out_size; (void)ws_size;
    const float* x     = (const float*)d_in[0];
    const float* in_w  = (const float*)d_in[1];
    const float* in_b  = (const float*)d_in[2];
    const float* ln_w  = (const float*)d_in[3];
    const float* ln_b  = (const float*)d_in[4];
    const float* inW   = (const float*)d_in[5];
    const float* convW = (const float*)d_in[6];
    const float* convB = (const float*)d_in[7];
    const float* xpW   = (const float*)d_in[8];
    const float* dtW   = (const float*)d_in[9];
    const float* A_log = (const float*)d_in[10];
    const float* Dv    = (const float*)d_in[11];
    const float* outW  = (const float*)d_in[12];
    const float* fln_w = (const float*)d_in[13];
    const float* fln_b = (const float*)d_in[14];
    const float* h1W   = (const float*)d_in[15];
    const float* h1b   = (const float*)d_in[16];
    const float* h2W   = (const float*)d_in[17];
    const float* h2b   = (const float*)d_in[18];
    const float* dtB   = (const float*)d_in[19];
    float* out = (float*)d_out;

    float* w = (float*)d_ws;
    float* hbuf = w;  w += ROWS * DM;
    float* xln  = w;  w += ROWS * DM;   // later aliased as S
    float* xs   = w;  w += ROWS * DI;   // later aliased as y
    float* z    = w;  w += ROWS * DI;
    float* xc   = w;  w += ROWS * DI;
    float* dt   = w;  w += ROWS * DI;
    float* xd   = w;  w += ROWS * XD;
    float* P    = w;  w += SCN * NC;
    short* inWt  = (short*)w;                  // [4][1024][256] bf16
    short* xpWt  = inWt + 4 * 1024 * DM;       // [4][64][512]  bf16 (padded from 48)
    short* outWt = xpWt + 4 * 64 * DI;         // [4][256][512] bf16
    float* y = xs;
    float* S = xln;

    // --- weight prep (bf16 transposes), independent of everything else ---
    for (int i = 0; i < NL; ++i) {
        wtrans<<<1024 * DM / 256, 256, 0, stream>>>(inW + i * DM * 2 * DI,
                                                    inWt + i * 1024 * DM, DM, 1024, 1024);
        wtrans<<<64 * DI / 256, 256, 0, stream>>>(xpW + i * DI * XD,
                                                  xpWt + i * 64 * DI, DI, XD, 64);
        wtrans<<<DM * DI / 256, 256, 0, stream>>>(outW + i * DI * DM,
                                                  outWt + i * DM * DI, DI, DM, DM);
    }

    // h = x @ in_w + in_b  (fp32, K=32 — tiny)
    gemm16<<<dim3(DM / 16, ROWS / 16), dim3(16, 16), 0, stream>>>(
        x, in_w, hbuf, in_b, ROWS, DM, NF, NF, DM, DM);

    for (int i = 0; i < NL; ++i) {
        layernorm_kernel<<<ROWS, DM, 0, stream>>>(hbuf, ln_w + i * DM, ln_b + i * DM, xln);

        // xz = xln @ inW[i] -> split xs | z   (MFMA bf16)
        gemm_mfma<0><<<dim3(1024 / 64, ROWS / 128), 256, 0, stream>>>(
            xln, inWt + i * 1024 * DM, xs, z, DM, DM, 0, 0);

        conv_silu_kernel<<<ROWS * DI / 256, 256, 0, stream>>>(
            xs, convW + i * 4 * DI, convB + i * DI, xc);

        // xd = xc @ xpW[i]   (MFMA bf16, N padded 48->64)
        gemm_mfma<1><<<dim3(1, ROWS / 128), 256, 0, stream>>>(
            xc, xpWt + i * 64 * DI, xd, nullptr, DI, DI, XD, XD);

        // dt = softplus(xd[:, :16] @ dtW[i] + dtB[i])  (exact fp32)
        dt_kernel<<<ROWS, DI, 0, stream>>>(xd, dtW + i * DR * DI, dtB + i * DI, dt);

        scan_pass1<<<NB * NC * (DI / 16), 256, 0, stream>>>(
            xd, dt, xc, A_log + i * DI * DS, P, S);
        scan_combine<<<SCN / 256, 256, 0, stream>>>(P, S);
        scan_pass2<<<NB * NC * (DI / 16), 256, 0, stream>>>(
            xd, dt, xc, A_log + i * DI * DS, Dv + i * DI, P, z, y);

        // h += y @ outW[i]   (MFMA bf16, accumulate)
        gemm_mfma<2><<<dim3(DM / 64, ROWS / 128), 256, 0, stream>>>(
            y, outWt + i * DM * DI, hbuf, nullptr, DI, DI, DM, 0);
    }

    head_kernel<<<NB, DM, 0, stream>>>(hbuf, fln_w, fln_b, h1W, h1b, h2W, h2b, out);
}

// Round 4
// 1963.268 us; speedup vs baseline: 3.8714x; 1.0542x over previous
//
#include <hip/hip_runtime.h>
#include <math.h>

namespace {

constexpr int NL = 4;      // layers
constexpr int DM = 256;    // d_model
constexpr int DI = 512;    // d_inner
constexpr int DS = 16;     // d_state
constexpr int DR = 16;     // dt_rank
constexpr int NF = 32;     // n_features
constexpr int NB = 8;      // batch
constexpr int T  = 2048;   // seq
constexpr int ROWS = NB * T;       // 16384
constexpr int XD = DR + 2 * DS;    // 48
constexpr int NC = 64;             // scan chunks
constexpr int CL = T / NC;         // 32 steps per chunk
constexpr int SCN = NB * DI * DS;  // 65536 scan lanes

constexpr float LOG2E = 1.44269504088896341f;
constexpr float LN2   = 0.69314718055994531f;

typedef __attribute__((ext_vector_type(4))) float f32x4;
typedef __attribute__((ext_vector_type(8))) short bf16x8;
typedef __attribute__((ext_vector_type(4))) short bf16x4;

__device__ __forceinline__ float fexp2(float x) { return __builtin_amdgcn_exp2f(x); }
__device__ __forceinline__ float frcp(float x)  { return __builtin_amdgcn_rcpf(x); }
__device__ __forceinline__ float flog2(float x) { return __builtin_amdgcn_logf(x); }

// fast silu: x * 1/(1+2^(-log2e*x))   (native exp/rcp, ~1ulp each)
__device__ __forceinline__ float siluf(float x) {
    return x * frcp(1.f + fexp2(-LOG2E * x));
}
// fast softplus: max(x,0) + ln2*log2(1+2^(-log2e*|x|))
__device__ __forceinline__ float softplusf(float x) {
    return fmaxf(x, 0.f) + LN2 * flog2(1.f + fexp2(-LOG2E * fabsf(x)));
}
__device__ __forceinline__ short f2bf(float f) {   // RNE float->bf16
    union { float f; unsigned u; } c; c.f = f;
    unsigned r = (c.u + 0x7FFFu + ((c.u >> 16) & 1u)) >> 16;
    return (short)r;
}

// ---------------------------------------------------------------------------
// fp32 16x16 GEMM — kept only for the tiny first projection (K=32).
// ---------------------------------------------------------------------------
__global__ void gemm16(const float* __restrict__ A, const float* __restrict__ B,
                       float* __restrict__ C, const float* __restrict__ bias,
                       int M, int N, int K, int lda, int ldb, int ldc)
{
    __shared__ float As[16][17];
    __shared__ float Bs[16][17];
    const int tx = threadIdx.x, ty = threadIdx.y;
    const int row = blockIdx.y * 16 + ty;
    const int col = blockIdx.x * 16 + tx;
    float acc = 0.f;
    for (int k0 = 0; k0 < K; k0 += 16) {
        As[ty][tx] = A[row * lda + k0 + tx];
        Bs[ty][tx] = B[(k0 + ty) * ldb + col];
        __syncthreads();
#pragma unroll
        for (int kk = 0; kk < 16; ++kk) acc += As[ty][kk] * Bs[kk][tx];
        __syncthreads();
    }
    C[row * ldc + col] = acc + bias[col];
}

// ---------------------------------------------------------------------------
// Weight prep: dst[Npad][K] (bf16) = transpose(src[K][N]), zero-pad n>=N.
// ---------------------------------------------------------------------------
__global__ void wtrans(const float* __restrict__ src, short* __restrict__ dst,
                       int K, int N, int Npad)
{
    const int idx = blockIdx.x * 256 + threadIdx.x;   // over Npad*K
    const unsigned n = (unsigned)idx / (unsigned)K;
    const unsigned k = (unsigned)idx - n * (unsigned)K;
    float v = (n < (unsigned)N) ? src[k * N + n] : 0.f;
    dst[idx] = f2bf(v);
}

// ---------------------------------------------------------------------------
// MFMA bf16 GEMM.  Tile 128x64, 4 waves, v_mfma_f32_16x16x32_bf16.
// EP 0: split write at col 512 -> C | C1    [in-proj]
// EP 1: C[row*ldc+col] = acc for col < Ncut [x-proj]
// EP 2: C[row*ldc+col] += acc               [out-proj]
// ---------------------------------------------------------------------------
template <int EP>
__global__ void gemm_mfma(const float* __restrict__ A, const short* __restrict__ Bt,
                          float* __restrict__ C, float* __restrict__ C1,
                          int K, int lda, int ldc, int Ncut)
{
    __shared__ short smem[7680];          // A: 128*40, B: 64*40 (shorts)
    const int tid = threadIdx.x;
    const int lane = tid & 63, w = tid >> 6;
    const int wr = w >> 1, wc = w & 1;
    const int lr = lane & 15, lk = lane >> 4;
    const int m0 = blockIdx.y * 128;
    const int n0 = blockIdx.x * 64;

    f32x4 acc[4][2] = {};
    for (int k0 = 0; k0 < K; k0 += 32) {
        __syncthreads();
#pragma unroll
        for (int i = 0; i < 4; ++i) {
            int c = tid + i * 256;
            int row = c >> 3, kc = c & 7;
            f32x4 v = *(const f32x4*)(A + (size_t)(m0 + row) * lda + k0 + kc * 4);
            bf16x4 o;
            o[0] = f2bf(v[0]); o[1] = f2bf(v[1]); o[2] = f2bf(v[2]); o[3] = f2bf(v[3]);
            *(bf16x4*)(&smem[row * 40 + kc * 4]) = o;
        }
        {
            int row = tid >> 2, kc = tid & 3;
            bf16x8 v = *(const bf16x8*)(Bt + (size_t)(n0 + row) * K + k0 + kc * 8);
            *(bf16x8*)(&smem[5120 + row * 40 + kc * 8]) = v;
        }
        __syncthreads();
        bf16x8 af[4], bfr[2];
#pragma unroll
        for (int m = 0; m < 4; ++m)
            af[m] = *(const bf16x8*)(&smem[(wr * 64 + m * 16 + lr) * 40 + lk * 8]);
#pragma unroll
        for (int n = 0; n < 2; ++n)
            bfr[n] = *(const bf16x8*)(&smem[5120 + (wc * 32 + n * 16 + lr) * 40 + lk * 8]);
#pragma unroll
        for (int m = 0; m < 4; ++m)
#pragma unroll
            for (int n = 0; n < 2; ++n)
                acc[m][n] = __builtin_amdgcn_mfma_f32_16x16x32_bf16(af[m], bfr[n], acc[m][n], 0, 0, 0);
    }
#pragma unroll
    for (int m = 0; m < 4; ++m) {
#pragma unroll
        for (int n = 0; n < 2; ++n) {
            const int col = n0 + wc * 32 + n * 16 + lr;
#pragma unroll
            for (int j = 0; j < 4; ++j) {
                const int row = m0 + wr * 64 + m * 16 + lk * 4 + j;
                const float v = acc[m][n][j];
                if (EP == 0) {
                    if (col < DI) C[(size_t)row * DI + col] = v;
                    else          C1[(size_t)row * DI + col - DI] = v;
                } else if (EP == 1) {
                    if (col < Ncut) C[(size_t)row * ldc + col] = v;
                } else {
                    C[(size_t)row * ldc + col] += v;
                }
            }
        }
    }
}

// ---------------------------------------------------------------------------
// dt = softplus(xd[:, :16] @ dtW + dtB) — exact fp32, K=16 dot per output.
// ---------------------------------------------------------------------------
__global__ void dt_kernel(const float* __restrict__ xd, const float* __restrict__ dtW,
                          const float* __restrict__ dtB, float* __restrict__ dt)
{
    const int row = blockIdx.x;
    const int d = threadIdx.x;
    __shared__ float xr[DR];
    if (d < DR) xr[d] = xd[row * XD + d];
    __syncthreads();
    float acc = dtB[d];
#pragma unroll
    for (int r = 0; r < DR; ++r) acc += xr[r] * dtW[r * DI + d];
    dt[(size_t)row * DI + d] = softplusf(acc);
}

// ---------------------------------------------------------------------------
// LayerNorm over last dim (256), one block of 256 threads per row.
// ---------------------------------------------------------------------------
__global__ void layernorm_kernel(const float* __restrict__ x,
                                 const float* __restrict__ w,
                                 const float* __restrict__ b,
                                 float* __restrict__ out)
{
    const int row = blockIdx.x;
    const int t = threadIdx.x;
    const int wid = t >> 6, lane = t & 63;
    __shared__ float red[4];

    float v = x[row * DM + t];
    float s = v;
#pragma unroll
    for (int o = 32; o >= 1; o >>= 1) s += __shfl_xor(s, o);
    if (lane == 0) red[wid] = s;
    __syncthreads();
    float mu = (red[0] + red[1] + red[2] + red[3]) * (1.f / DM);
    __syncthreads();

    float d = v - mu;
    float q = d * d;
#pragma unroll
    for (int o = 32; o >= 1; o >>= 1) q += __shfl_xor(q, o);
    if (lane == 0) red[wid] = q;
    __syncthreads();
    float var = (red[0] + red[1] + red[2] + red[3]) * (1.f / DM);

    out[row * DM + t] = d * (1.f / sqrtf(var + 1e-5f)) * w[t] + b[t];
}

// ---------------------------------------------------------------------------
// Depthwise causal conv (width 4) + bias + SiLU (fast).
// ---------------------------------------------------------------------------
__global__ void conv_silu_kernel(const float* __restrict__ xs,
                                 const float* __restrict__ W,   // [4, DI]
                                 const float* __restrict__ Bc,  // [DI]
                                 float* __restrict__ xc)
{
    const int idx = blockIdx.x * blockDim.x + threadIdx.x;
    const int c = idx & (DI - 1);
    const int bt = idx >> 9;
    const int t = bt & (T - 1);
    float acc = Bc[c];
#pragma unroll
    for (int k = 0; k < 4; ++k) {
        int tt = t + k - 3;
        if (tt >= 0) acc += xs[(bt + k - 3) * DI + c] * W[k * DI + c];
    }
    xc[idx] = siluf(acc);
}

// ---------------------------------------------------------------------------
// Chunked selective scan (pass1 / combine / pass2, gate fused in pass2).
// All exps are native exp2 with log2e folded into A2.
// ---------------------------------------------------------------------------
__global__ void scan_pass1(const float* __restrict__ xd,
                           const float* __restrict__ dt,
                           const float* __restrict__ xc,
                           const float* __restrict__ A_log,
                           float* __restrict__ P, float* __restrict__ S)
{
    const int s   = threadIdx.x & 15;
    const int dlo = threadIdx.x >> 4;
    const int dblk = blockIdx.x & 31;
    const int c    = (blockIdx.x >> 5) & (NC - 1);
    const int b    = blockIdx.x >> 11;
    const int d = dblk * 16 + dlo;

    // A2 = -exp(A_log) * log2(e)
    const float A2 = -LOG2E * fexp2(LOG2E * A_log[d * DS + s]);
    float sdt = 0.f, sacc = 0.f;
    const int row0 = b * T + c * CL;
#pragma unroll 4
    for (int t = 0; t < CL; ++t) {
        const int row = row0 + t;
        float dtv = dt[row * DI + d];
        float xcv = xc[row * DI + d];
        float Bm  = xd[row * XD + DR + s];
        float a = fexp2(dtv * A2);
        sacc = a * sacc + dtv * Bm * xcv;
        sdt += dtv;
    }
    const int idx3 = (b * DI + d) * DS + s;
    P[c * SCN + idx3] = fexp2(A2 * sdt);   // product of all a's
    S[c * SCN + idx3] = sacc;
}

__global__ void scan_combine(float* __restrict__ P, const float* __restrict__ S)
{
    const int idx3 = blockIdx.x * blockDim.x + threadIdx.x;
    float h = 0.f;
    for (int c = 0; c < NC; ++c) {
        float pc = P[c * SCN + idx3];
        float sc = S[c * SCN + idx3];
        P[c * SCN + idx3] = h;
        h = pc * h + sc;
    }
}

__global__ void scan_pass2(const float* __restrict__ xd,
                           const float* __restrict__ dt,
                           const float* __restrict__ xc,
                           const float* __restrict__ A_log,
                           const float* __restrict__ Dv,
                           const float* __restrict__ H,
                           const float* __restrict__ z,
                           float* __restrict__ y)
{
    const int s   = threadIdx.x & 15;
    const int dlo = threadIdx.x >> 4;
    const int dblk = blockIdx.x & 31;
    const int c    = (blockIdx.x >> 5) & (NC - 1);
    const int b    = blockIdx.x >> 11;
    const int d = dblk * 16 + dlo;

    const float A2 = -LOG2E * fexp2(LOG2E * A_log[d * DS + s]);
    const float Dd = Dv[d];
    const int idx3 = (b * DI + d) * DS + s;
    float h = H[c * SCN + idx3];
    const int row0 = b * T + c * CL;
#pragma unroll 4
    for (int t = 0; t < CL; ++t) {
        const int row = row0 + t;
        float dtv = dt[row * DI + d];
        float xcv = xc[row * DI + d];
        float Bm  = xd[row * XD + DR + s];
        float Cm  = xd[row * XD + DR + DS + s];
        float a = fexp2(dtv * A2);
        h = a * h + dtv * Bm * xcv;
        float pv = h * Cm;
        pv += __shfl_xor(pv, 1);
        pv += __shfl_xor(pv, 2);
        pv += __shfl_xor(pv, 4);
        pv += __shfl_xor(pv, 8);
        if (s == 0) {
            float zv = z[row * DI + d];
            y[row * DI + d] = (pv + xcv * Dd) * siluf(zv);
        }
    }
}

// ---------------------------------------------------------------------------
// Head: final LN on last token, gelu(last@h1W+h1b) @ h2W + h2b.
// ---------------------------------------------------------------------------
__global__ void head_kernel(const float* __restrict__ h,
                            const float* __restrict__ fw, const float* __restrict__ fb,
                            const float* __restrict__ h1W, const float* __restrict__ h1b,
                            const float* __restrict__ h2W, const float* __restrict__ h2b,
                            float* __restrict__ out)
{
    const int bi = blockIdx.x;
    const int t = threadIdx.x;
    const int wid = t >> 6, lane = t & 63;
    __shared__ float red[4];
    __shared__ float ln[DM];
    __shared__ float hid[DM / 2];

    const float* row = h + ((bi + 1) * T - 1) * DM;
    float v = row[t];
    float s = v;
#pragma unroll
    for (int o = 32; o >= 1; o >>= 1) s += __shfl_xor(s, o);
    if (lane == 0) red[wid] = s;
    __syncthreads();
    float mu = (red[0] + red[1] + red[2] + red[3]) * (1.f / DM);
    __syncthreads();
    float d = v - mu;
    float q = d * d;
#pragma unroll
    for (int o = 32; o >= 1; o >>= 1) q += __shfl_xor(q, o);
    if (lane == 0) red[wid] = q;
    __syncthreads();
    float var = (red[0] + red[1] + red[2] + red[3]) * (1.f / DM);
    ln[t] = d * (1.f / sqrtf(var + 1e-5f)) * fw[t] + fb[t];
    __syncthreads();

    if (t < DM / 2) {
        float acc = h1b[t];
        for (int k = 0; k < DM; ++k) acc += ln[k] * h1W[k * (DM / 2) + t];
        float x3 = acc * acc * acc;
        hid[t] = 0.5f * acc * (1.f + tanhf(0.7978845608028654f * (acc + 0.044715f * x3)));
    }
    __syncthreads();
    if (t < 3) {
        float acc = h2b[t];
        for (int k = 0; k < DM / 2; ++k) acc += hid[k] * h2W[k * 3 + t];
        out[bi * 3 + t] = acc;
    }
}

} // namespace

extern "C" void kernel_launch(void* const* d_in, const int* in_sizes, int n_in,
                              void* d_out, int out_size, void* d_ws, size_t ws_size,
                              hipStream_t stream)
{
    (void)in_sizes; (void)n_in; (void)out_size; (void)ws_size;
    const float* x     = (const float*)d_in[0];
    const float* in_w  = (const float*)d_in[1];
    const float* in_b  = (const float*)d_in[2];
    const float* ln_w  = (const float*)d_in[3];
    const float* ln_b  = (const float*)d_in[4];
    const float* inW   = (const float*)d_in[5];
    const float* convW = (const float*)d_in[6];
    const float* convB = (const float*)d_in[7];
    const float* xpW   = (const float*)d_in[8];
    const float* dtW   = (const float*)d_in[9];
    const float* A_log = (const float*)d_in[10];
    const float* Dv    = (const float*)d_in[11];
    const float* outW  = (const float*)d_in[12];
    const float* fln_w = (const float*)d_in[13];
    const float* fln_b = (const float*)d_in[14];
    const float* h1W   = (const float*)d_in[15];
    const float* h1b   = (const float*)d_in[16];
    const float* h2W   = (const float*)d_in[17];
    const float* h2b   = (const float*)d_in[18];
    const float* dtB   = (const float*)d_in[19];
    float* out = (float*)d_out;

    float* w = (float*)d_ws;
    float* hbuf = w;  w += ROWS * DM;
    float* xln  = w;  w += ROWS * DM;   // later aliased as S
    float* xs   = w;  w += ROWS * DI;   // later aliased as y
    float* z    = w;  w += ROWS * DI;
    float* xc   = w;  w += ROWS * DI;
    float* dt   = w;  w += ROWS * DI;
    float* xd   = w;  w += ROWS * XD;
    float* P    = w;  w += SCN * NC;
    short* inWt  = (short*)w;                  // [4][1024][256] bf16
    short* xpWt  = inWt + 4 * 1024 * DM;       // [4][64][512]  bf16 (padded from 48)
    short* outWt = xpWt + 4 * 64 * DI;         // [4][256][512] bf16
    float* y = xs;
    float* S = xln;

    for (int i = 0; i < NL; ++i) {
        wtrans<<<1024 * DM / 256, 256, 0, stream>>>(inW + i * DM * 2 * DI,
                                                    inWt + i * 1024 * DM, DM, 1024, 1024);
        wtrans<<<64 * DI / 256, 256, 0, stream>>>(xpW + i * DI * XD,
                                                  xpWt + i * 64 * DI, DI, XD, 64);
        wtrans<<<DM * DI / 256, 256, 0, stream>>>(outW + i * DI * DM,
                                                  outWt + i * DM * DI, DI, DM, DM);
    }

    gemm16<<<dim3(DM / 16, ROWS / 16), dim3(16, 16), 0, stream>>>(
        x, in_w, hbuf, in_b, ROWS, DM, NF, NF, DM, DM);

    for (int i = 0; i < NL; ++i) {
        layernorm_kernel<<<ROWS, DM, 0, stream>>>(hbuf, ln_w + i * DM, ln_b + i * DM, xln);

        gemm_mfma<0><<<dim3(1024 / 64, ROWS / 128), 256, 0, stream>>>(
            xln, inWt + i * 1024 * DM, xs, z, DM, DM, 0, 0);

        conv_silu_kernel<<<ROWS * DI / 256, 256, 0, stream>>>(
            xs, convW + i * 4 * DI, convB + i * DI, xc);

        gemm_mfma<1><<<dim3(1, ROWS / 128), 256, 0, stream>>>(
            xc, xpWt + i * 64 * DI, xd, nullptr, DI, DI, XD, XD);

        dt_kernel<<<ROWS, DI, 0, stream>>>(xd, dtW + i * DR * DI, dtB + i * DI, dt);

        scan_pass1<<<NB * NC * (DI / 16), 256, 0, stream>>>(
            xd, dt, xc, A_log + i * DI * DS, P, S);
        scan_combine<<<SCN / 256, 256, 0, stream>>>(P, S);
        scan_pass2<<<NB * NC * (DI / 16), 256, 0, stream>>>(
            xd, dt, xc, A_log + i * DI * DS, Dv + i * DI, P, z, y);

        gemm_mfma<2><<<dim3(DM / 64, ROWS / 128), 256, 0, stream>>>(
            y, outWt + i * DM * DI, hbuf, nullptr, DI, DI, DM, 0);
    }

    head_kernel<<<NB, DM, 0, stream>>>(hbuf, fln_w, fln_b, h1W, h1b, h2W, h2b, out);
}

// Round 5
// 1105.533 us; speedup vs baseline: 6.8751x; 1.7759x over previous
//
#include <hip/hip_runtime.h>
#include <math.h>

namespace {

constexpr int NL = 4;      // layers
constexpr int DM = 256;    // d_model
constexpr int DI = 512;    // d_inner
constexpr int DS = 16;     // d_state
constexpr int DR = 16;     // dt_rank
constexpr int NF = 32;     // n_features
constexpr int NB = 8;      // batch
constexpr int T  = 2048;   // seq
constexpr int ROWS = NB * T;       // 16384
constexpr int XD = DR + 2 * DS;    // 48
constexpr int NC = 64;             // scan chunks
constexpr int CL = T / NC;         // 32 steps per chunk
constexpr int SCN = NB * DI * DS;  // 65536 scan states

constexpr float LOG2E = 1.44269504088896341f;
constexpr float LN2   = 0.69314718055994531f;

typedef __attribute__((ext_vector_type(4))) float f32x4;
typedef __attribute__((ext_vector_type(8))) short bf16x8;
typedef __attribute__((ext_vector_type(4))) short bf16x4;

__device__ __forceinline__ float fexp2(float x) { return __builtin_amdgcn_exp2f(x); }
__device__ __forceinline__ float frcp(float x)  { return __builtin_amdgcn_rcpf(x); }
__device__ __forceinline__ float flog2(float x) { return __builtin_amdgcn_logf(x); }

__device__ __forceinline__ float siluf(float x) {
    return x * frcp(1.f + fexp2(-LOG2E * x));
}
__device__ __forceinline__ float softplusf(float x) {
    return fmaxf(x, 0.f) + LN2 * flog2(1.f + fexp2(-LOG2E * fabsf(x)));
}
__device__ __forceinline__ short f2bf(float f) {   // RNE float->bf16
    union { float f; unsigned u; } c; c.f = f;
    unsigned r = (c.u + 0x7FFFu + ((c.u >> 16) & 1u)) >> 16;
    return (short)r;
}

// ---------------------------------------------------------------------------
// fp32 16x16 GEMM — kept only for the tiny first projection (K=32).
// ---------------------------------------------------------------------------
__global__ void gemm16(const float* __restrict__ A, const float* __restrict__ B,
                       float* __restrict__ C, const float* __restrict__ bias,
                       int M, int N, int K, int lda, int ldb, int ldc)
{
    __shared__ float As[16][17];
    __shared__ float Bs[16][17];
    const int tx = threadIdx.x, ty = threadIdx.y;
    const int row = blockIdx.y * 16 + ty;
    const int col = blockIdx.x * 16 + tx;
    float acc = 0.f;
    for (int k0 = 0; k0 < K; k0 += 16) {
        As[ty][tx] = A[row * lda + k0 + tx];
        Bs[ty][tx] = B[(k0 + ty) * ldb + col];
        __syncthreads();
#pragma unroll
        for (int kk = 0; kk < 16; ++kk) acc += As[ty][kk] * Bs[kk][tx];
        __syncthreads();
    }
    C[row * ldc + col] = acc + bias[col];
}

// ---------------------------------------------------------------------------
// Weight prep: dst[Npad][K] (bf16) = transpose(src[K][N]), zero-pad n>=N.
// ---------------------------------------------------------------------------
__global__ void wtrans(const float* __restrict__ src, short* __restrict__ dst,
                       int K, int N, int Npad)
{
    const int idx = blockIdx.x * 256 + threadIdx.x;   // over Npad*K
    const unsigned n = (unsigned)idx / (unsigned)K;
    const unsigned k = (unsigned)idx - n * (unsigned)K;
    float v = (n < (unsigned)N) ? src[k * N + n] : 0.f;
    dst[idx] = f2bf(v);
}

// ---------------------------------------------------------------------------
// negA2[l][d][s] = -log2(e) * exp(A_log[l][d][s])
// ---------------------------------------------------------------------------
__global__ void prep_A2(const float* __restrict__ A_log, float* __restrict__ negA2)
{
    const int i = blockIdx.x * 256 + threadIdx.x;     // NL*DI*DS
    negA2[i] = -LOG2E * fexp2(LOG2E * A_log[i]);
}

// ---------------------------------------------------------------------------
// MFMA bf16 GEMM.  Tile 128x64, 4 waves, v_mfma_f32_16x16x32_bf16.
// EP 0: split write at col 512 -> C | C1    [in-proj]
// EP 1: C[row*ldc+col] = acc for col < Ncut [x-proj]
// EP 2: C[row*ldc+col] += acc               [out-proj]
// ---------------------------------------------------------------------------
template <int EP>
__global__ void gemm_mfma(const float* __restrict__ A, const short* __restrict__ Bt,
                          float* __restrict__ C, float* __restrict__ C1,
                          int K, int lda, int ldc, int Ncut)
{
    __shared__ short smem[7680];          // A: 128*40, B: 64*40 (shorts)
    const int tid = threadIdx.x;
    const int lane = tid & 63, w = tid >> 6;
    const int wr = w >> 1, wc = w & 1;
    const int lr = lane & 15, lk = lane >> 4;
    const int m0 = blockIdx.y * 128;
    const int n0 = blockIdx.x * 64;

    f32x4 acc[4][2] = {};
    for (int k0 = 0; k0 < K; k0 += 32) {
        __syncthreads();
#pragma unroll
        for (int i = 0; i < 4; ++i) {
            int c = tid + i * 256;
            int row = c >> 3, kc = c & 7;
            f32x4 v = *(const f32x4*)(A + (size_t)(m0 + row) * lda + k0 + kc * 4);
            bf16x4 o;
            o[0] = f2bf(v[0]); o[1] = f2bf(v[1]); o[2] = f2bf(v[2]); o[3] = f2bf(v[3]);
            *(bf16x4*)(&smem[row * 40 + kc * 4]) = o;
        }
        {
            int row = tid >> 2, kc = tid & 3;
            bf16x8 v = *(const bf16x8*)(Bt + (size_t)(n0 + row) * K + k0 + kc * 8);
            *(bf16x8*)(&smem[5120 + row * 40 + kc * 8]) = v;
        }
        __syncthreads();
        bf16x8 af[4], bfr[2];
#pragma unroll
        for (int m = 0; m < 4; ++m)
            af[m] = *(const bf16x8*)(&smem[(wr * 64 + m * 16 + lr) * 40 + lk * 8]);
#pragma unroll
        for (int n = 0; n < 2; ++n)
            bfr[n] = *(const bf16x8*)(&smem[5120 + (wc * 32 + n * 16 + lr) * 40 + lk * 8]);
#pragma unroll
        for (int m = 0; m < 4; ++m)
#pragma unroll
            for (int n = 0; n < 2; ++n)
                acc[m][n] = __builtin_amdgcn_mfma_f32_16x16x32_bf16(af[m], bfr[n], acc[m][n], 0, 0, 0);
    }
#pragma unroll
    for (int m = 0; m < 4; ++m) {
#pragma unroll
        for (int n = 0; n < 2; ++n) {
            const int col = n0 + wc * 32 + n * 16 + lr;
#pragma unroll
            for (int j = 0; j < 4; ++j) {
                const int row = m0 + wr * 64 + m * 16 + lk * 4 + j;
                const float v = acc[m][n][j];
                if (EP == 0) {
                    if (col < DI) C[(size_t)row * DI + col] = v;
                    else          C1[(size_t)row * DI + col - DI] = v;
                } else if (EP == 1) {
                    if (col < Ncut) C[(size_t)row * ldc + col] = v;
                } else {
                    C[(size_t)row * ldc + col] += v;
                }
            }
        }
    }
}

// ---------------------------------------------------------------------------
// dt = softplus(xd[:, :16] @ dtW + dtB) — exact fp32, K=16 dot per output.
// ---------------------------------------------------------------------------
__global__ void dt_kernel(const float* __restrict__ xd, const float* __restrict__ dtW,
                          const float* __restrict__ dtB, float* __restrict__ dt)
{
    const int row = blockIdx.x;
    const int d = threadIdx.x;
    __shared__ float xr[DR];
    if (d < DR) xr[d] = xd[row * XD + d];
    __syncthreads();
    float acc = dtB[d];
#pragma unroll
    for (int r = 0; r < DR; ++r) acc += xr[r] * dtW[r * DI + d];
    dt[(size_t)row * DI + d] = softplusf(acc);
}

// ---------------------------------------------------------------------------
// LayerNorm over last dim (256), one block of 256 threads per row.
// ---------------------------------------------------------------------------
__global__ void layernorm_kernel(const float* __restrict__ x,
                                 const float* __restrict__ w,
                                 const float* __restrict__ b,
                                 float* __restrict__ out)
{
    const int row = blockIdx.x;
    const int t = threadIdx.x;
    const int wid = t >> 6, lane = t & 63;
    __shared__ float red[4];

    float v = x[row * DM + t];
    float s = v;
#pragma unroll
    for (int o = 32; o >= 1; o >>= 1) s += __shfl_xor(s, o);
    if (lane == 0) red[wid] = s;
    __syncthreads();
    float mu = (red[0] + red[1] + red[2] + red[3]) * (1.f / DM);
    __syncthreads();

    float d = v - mu;
    float q = d * d;
#pragma unroll
    for (int o = 32; o >= 1; o >>= 1) q += __shfl_xor(q, o);
    if (lane == 0) red[wid] = q;
    __syncthreads();
    float var = (red[0] + red[1] + red[2] + red[3]) * (1.f / DM);

    out[row * DM + t] = d * (1.f / sqrtf(var + 1e-5f)) * w[t] + b[t];
}

// ---------------------------------------------------------------------------
// Depthwise causal conv (width 4) + bias + SiLU (fast).
// ---------------------------------------------------------------------------
__global__ void conv_silu_kernel(const float* __restrict__ xs,
                                 const float* __restrict__ W,   // [4, DI]
                                 const float* __restrict__ Bc,  // [DI]
                                 float* __restrict__ xc)
{
    const int idx = blockIdx.x * blockDim.x + threadIdx.x;
    const int c = idx & (DI - 1);
    const int bt = idx >> 9;
    const int t = bt & (T - 1);
    float acc = Bc[c];
#pragma unroll
    for (int k = 0; k < 4; ++k) {
        int tt = t + k - 3;
        if (tt >= 0) acc += xs[(bt + k - 3) * DI + c] * W[k * DI + c];
    }
    xc[idx] = siluf(acc);
}

// ---------------------------------------------------------------------------
// Chunked selective scan, lane-per-d mapping: each thread owns one d channel
// and keeps all 16 h-states in registers.  dt/xc/z/y accesses are coalesced
// row-major; Bm/Cm staged to LDS per chunk (wave-uniform broadcast reads).
// ---------------------------------------------------------------------------
__global__ void scan_pass1(const float* __restrict__ xd,
                           const float* __restrict__ dtp,
                           const float* __restrict__ xc,
                           const float* __restrict__ negA2,  // [DI*DS] (layer slice)
                           float* __restrict__ P, float* __restrict__ S)
{
    __shared__ float ldsB[CL][DS];
    const int d = blockIdx.x * 256 + threadIdx.x;
    const int c = blockIdx.y;
    const int b = blockIdx.z;
    const int row0 = b * T + c * CL;

    if (threadIdx.x < CL * DS / 4) {
        int t = threadIdx.x >> 2, q = threadIdx.x & 3;
        *(f32x4*)&ldsB[t][q * 4] =
            *(const f32x4*)(xd + (size_t)(row0 + t) * XD + DR + q * 4);
    }
    float A2[DS], h[DS];
#pragma unroll
    for (int q = 0; q < 4; ++q)
        *(f32x4*)&A2[q * 4] = *(const f32x4*)(negA2 + d * DS + q * 4);
#pragma unroll
    for (int s = 0; s < DS; ++s) h[s] = 0.f;
    float sdt = 0.f;
    __syncthreads();

    for (int t = 0; t < CL; ++t) {
        const int row = row0 + t;
        float dtv = dtp[(size_t)row * DI + d];
        float xcv = xc[(size_t)row * DI + d];
        float dx = dtv * xcv;
        sdt += dtv;
#pragma unroll
        for (int s = 0; s < DS; ++s) {
            float a = fexp2(dtv * A2[s]);
            h[s] = a * h[s] + dx * ldsB[t][s];
        }
    }
    const size_t base = (size_t)c * SCN + ((size_t)b * DI + d) * DS;
#pragma unroll
    for (int q = 0; q < 4; ++q) {
        f32x4 hp, pp;
#pragma unroll
        for (int j = 0; j < 4; ++j) {
            hp[j] = h[q * 4 + j];
            pp[j] = fexp2(A2[q * 4 + j] * sdt);
        }
        *(f32x4*)(S + base + q * 4) = hp;
        *(f32x4*)(P + base + q * 4) = pp;
    }
}

__global__ void scan_combine(float* __restrict__ P, const float* __restrict__ S)
{
    const int idx3 = blockIdx.x * blockDim.x + threadIdx.x;
    float h = 0.f;
    for (int c = 0; c < NC; ++c) {
        float pc = P[c * SCN + idx3];
        float sc = S[c * SCN + idx3];
        P[c * SCN + idx3] = h;
        h = pc * h + sc;
    }
}

__global__ void scan_pass2(const float* __restrict__ xd,
                           const float* __restrict__ dtp,
                           const float* __restrict__ xc,
                           const float* __restrict__ negA2,
                           const float* __restrict__ Dv,
                           const float* __restrict__ H,   // [NC][SCN] (=P)
                           const float* __restrict__ z,
                           float* __restrict__ y)
{
    __shared__ float ldsB[CL][DS];
    __shared__ float ldsC[CL][DS];
    const int d = blockIdx.x * 256 + threadIdx.x;
    const int c = blockIdx.y;
    const int b = blockIdx.z;
    const int row0 = b * T + c * CL;

    {
        int t = (threadIdx.x & 127) >> 2, q = threadIdx.x & 3;
        const float* src = xd + (size_t)(row0 + t) * XD + DR +
                           (threadIdx.x < 128 ? 0 : DS) + q * 4;
        float* dst = (threadIdx.x < 128) ? &ldsB[t][q * 4] : &ldsC[t][q * 4];
        *(f32x4*)dst = *(const f32x4*)src;
    }
    float A2[DS], h[DS];
#pragma unroll
    for (int q = 0; q < 4; ++q)
        *(f32x4*)&A2[q * 4] = *(const f32x4*)(negA2 + d * DS + q * 4);
    const size_t base = (size_t)c * SCN + ((size_t)b * DI + d) * DS;
#pragma unroll
    for (int q = 0; q < 4; ++q)
        *(f32x4*)&h[q * 4] = *(const f32x4*)(H + base + q * 4);
    const float Dd = Dv[d];
    __syncthreads();

    for (int t = 0; t < CL; ++t) {
        const int row = row0 + t;
        float dtv = dtp[(size_t)row * DI + d];
        float xcv = xc[(size_t)row * DI + d];
        float zv  = z[(size_t)row * DI + d];
        float dx = dtv * xcv;
        float acc0 = 0.f, acc1 = 0.f, acc2 = 0.f, acc3 = 0.f;
#pragma unroll
        for (int s = 0; s < DS; s += 4) {
            float a0 = fexp2(dtv * A2[s + 0]);
            h[s + 0] = a0 * h[s + 0] + dx * ldsB[t][s + 0];
            acc0 += h[s + 0] * ldsC[t][s + 0];
            float a1 = fexp2(dtv * A2[s + 1]);
            h[s + 1] = a1 * h[s + 1] + dx * ldsB[t][s + 1];
            acc1 += h[s + 1] * ldsC[t][s + 1];
            float a2 = fexp2(dtv * A2[s + 2]);
            h[s + 2] = a2 * h[s + 2] + dx * ldsB[t][s + 2];
            acc2 += h[s + 2] * ldsC[t][s + 2];
            float a3 = fexp2(dtv * A2[s + 3]);
            h[s + 3] = a3 * h[s + 3] + dx * ldsB[t][s + 3];
            acc3 += h[s + 3] * ldsC[t][s + 3];
        }
        float yv = (acc0 + acc1) + (acc2 + acc3);
        y[(size_t)row * DI + d] = (yv + xcv * Dd) * siluf(zv);
    }
}

// ---------------------------------------------------------------------------
// Head: final LN on last token, gelu(last@h1W+h1b) @ h2W + h2b.
// ---------------------------------------------------------------------------
__global__ void head_kernel(const float* __restrict__ h,
                            const float* __restrict__ fw, const float* __restrict__ fb,
                            const float* __restrict__ h1W, const float* __restrict__ h1b,
                            const float* __restrict__ h2W, const float* __restrict__ h2b,
                            float* __restrict__ out)
{
    const int bi = blockIdx.x;
    const int t = threadIdx.x;
    const int wid = t >> 6, lane = t & 63;
    __shared__ float red[4];
    __shared__ float ln[DM];
    __shared__ float hid[DM / 2];

    const float* row = h + ((bi + 1) * T - 1) * DM;
    float v = row[t];
    float s = v;
#pragma unroll
    for (int o = 32; o >= 1; o >>= 1) s += __shfl_xor(s, o);
    if (lane == 0) red[wid] = s;
    __syncthreads();
    float mu = (red[0] + red[1] + red[2] + red[3]) * (1.f / DM);
    __syncthreads();
    float d = v - mu;
    float q = d * d;
#pragma unroll
    for (int o = 32; o >= 1; o >>= 1) q += __shfl_xor(q, o);
    if (lane == 0) red[wid] = q;
    __syncthreads();
    float var = (red[0] + red[1] + red[2] + red[3]) * (1.f / DM);
    ln[t] = d * (1.f / sqrtf(var + 1e-5f)) * fw[t] + fb[t];
    __syncthreads();

    if (t < DM / 2) {
        float acc = h1b[t];
        for (int k = 0; k < DM; ++k) acc += ln[k] * h1W[k * (DM / 2) + t];
        float x3 = acc * acc * acc;
        hid[t] = 0.5f * acc * (1.f + tanhf(0.7978845608028654f * (acc + 0.044715f * x3)));
    }
    __syncthreads();
    if (t < 3) {
        float acc = h2b[t];
        for (int k = 0; k < DM / 2; ++k) acc += hid[k] * h2W[k * 3 + t];
        out[bi * 3 + t] = acc;
    }
}

} // namespace

extern "C" void kernel_launch(void* const* d_in, const int* in_sizes, int n_in,
                              void* d_out, int out_size, void* d_ws, size_t ws_size,
                              hipStream_t stream)
{
    (void)in_sizes; (void)n_in; (void)out_size; (void)ws_size;
    const float* x     = (const float*)d_in[0];
    const float* in_w  = (const float*)d_in[1];
    const float* in_b  = (const float*)d_in[2];
    const float* ln_w  = (const float*)d_in[3];
    const float* ln_b  = (const float*)d_in[4];
    const float* inW   = (const float*)d_in[5];
    const float* convW = (const float*)d_in[6];
    const float* convB = (const float*)d_in[7];
    const float* xpW   = (const float*)d_in[8];
    const float* dtW   = (const float*)d_in[9];
    const float* A_log = (const float*)d_in[10];
    const float* Dv    = (const float*)d_in[11];
    const float* outW  = (const float*)d_in[12];
    const float* fln_w = (const float*)d_in[13];
    const float* fln_b = (const float*)d_in[14];
    const float* h1W   = (const float*)d_in[15];
    const float* h1b   = (const float*)d_in[16];
    const float* h2W   = (const float*)d_in[17];
    const float* h2b   = (const float*)d_in[18];
    const float* dtB   = (const float*)d_in[19];
    float* out = (float*)d_out;

    float* w = (float*)d_ws;
    float* hbuf = w;  w += ROWS * DM;
    float* xln  = w;  w += ROWS * DM;   // later aliased as S
    float* xs   = w;  w += ROWS * DI;   // later aliased as y
    float* z    = w;  w += ROWS * DI;
    float* xc   = w;  w += ROWS * DI;
    float* dt   = w;  w += ROWS * DI;
    float* xd   = w;  w += ROWS * XD;
    float* P    = w;  w += SCN * NC;
    float* negA2 = w; w += NL * DI * DS;
    short* inWt  = (short*)w;                  // [4][1024][256] bf16
    short* xpWt  = inWt + 4 * 1024 * DM;       // [4][64][512]  bf16 (padded from 48)
    short* outWt = xpWt + 4 * 64 * DI;         // [4][256][512] bf16
    float* y = xs;
    float* S = xln;

    for (int i = 0; i < NL; ++i) {
        wtrans<<<1024 * DM / 256, 256, 0, stream>>>(inW + i * DM * 2 * DI,
                                                    inWt + i * 1024 * DM, DM, 1024, 1024);
        wtrans<<<64 * DI / 256, 256, 0, stream>>>(xpW + i * DI * XD,
                                                  xpWt + i * 64 * DI, DI, XD, 64);
        wtrans<<<DM * DI / 256, 256, 0, stream>>>(outW + i * DI * DM,
                                                  outWt + i * DM * DI, DI, DM, DM);
    }
    prep_A2<<<NL * DI * DS / 256, 256, 0, stream>>>(A_log, negA2);

    gemm16<<<dim3(DM / 16, ROWS / 16), dim3(16, 16), 0, stream>>>(
        x, in_w, hbuf, in_b, ROWS, DM, NF, NF, DM, DM);

    for (int i = 0; i < NL; ++i) {
        layernorm_kernel<<<ROWS, DM, 0, stream>>>(hbuf, ln_w + i * DM, ln_b + i * DM, xln);

        gemm_mfma<0><<<dim3(1024 / 64, ROWS / 128), 256, 0, stream>>>(
            xln, inWt + i * 1024 * DM, xs, z, DM, DM, 0, 0);

        conv_silu_kernel<<<ROWS * DI / 256, 256, 0, stream>>>(
            xs, convW + i * 4 * DI, convB + i * DI, xc);

        gemm_mfma<1><<<dim3(1, ROWS / 128), 256, 0, stream>>>(
            xc, xpWt + i * 64 * DI, xd, nullptr, DI, DI, XD, XD);

        dt_kernel<<<ROWS, DI, 0, stream>>>(xd, dtW + i * DR * DI, dtB + i * DI, dt);

        scan_pass1<<<dim3(DI / 256, NC, NB), 256, 0, stream>>>(
            xd, dt, xc, negA2 + i * DI * DS, P, S);
        scan_combine<<<SCN / 256, 256, 0, stream>>>(P, S);
        scan_pass2<<<dim3(DI / 256, NC, NB), 256, 0, stream>>>(
            xd, dt, xc, negA2 + i * DI * DS, Dv + i * DI, P, z, y);

        gemm_mfma<2><<<dim3(DM / 64, ROWS / 128), 256, 0, stream>>>(
            y, outWt + i * DM * DI, hbuf, nullptr, DI, DI, DM, 0);
    }

    head_kernel<<<NB, DM, 0, stream>>>(hbuf, fln_w, fln_b, h1W, h1b, h2W, h2b, out);
}

// Round 6
// 815.830 us; speedup vs baseline: 9.3164x; 1.3551x over previous
//
#include <hip/hip_runtime.h>
#include <math.h>

namespace {

constexpr int NL = 4;      // layers
constexpr int DM = 256;    // d_model
constexpr int DI = 512;    // d_inner
constexpr int DS = 16;     // d_state
constexpr int DR = 16;     // dt_rank
constexpr int NF = 32;     // n_features
constexpr int NB = 8;      // batch
constexpr int T  = 2048;   // seq
constexpr int ROWS = NB * T;       // 16384
constexpr int XD = DR + 2 * DS;    // 48
constexpr int NC = 64;             // scan chunks
constexpr int CL = T / NC;         // 32 steps per chunk
constexpr int SCN = NB * DI * DS;  // 65536 scan states

constexpr float LOG2E = 1.44269504088896341f;
constexpr float LN2   = 0.69314718055994531f;

typedef __attribute__((ext_vector_type(4))) float f32x4;
typedef __attribute__((ext_vector_type(8))) short bf16x8;

__device__ __forceinline__ float fexp2(float x) { return __builtin_amdgcn_exp2f(x); }
__device__ __forceinline__ float frcp(float x)  { return __builtin_amdgcn_rcpf(x); }
__device__ __forceinline__ float flog2(float x) { return __builtin_amdgcn_logf(x); }

__device__ __forceinline__ float siluf(float x) {
    return x * frcp(1.f + fexp2(-LOG2E * x));
}
__device__ __forceinline__ float softplusf(float x) {
    return fmaxf(x, 0.f) + LN2 * flog2(1.f + fexp2(-LOG2E * fabsf(x)));
}
__device__ __forceinline__ short f2bf(float f) {   // RNE float->bf16
    union { float f; unsigned u; } c; c.f = f;
    unsigned r = (c.u + 0x7FFFu + ((c.u >> 16) & 1u)) >> 16;
    return (short)r;
}

// ---------------------------------------------------------------------------
// Weight prep: dst[l][Npad][K] (bf16) = transpose(src[l][K][N]); pad n>=N.
// ---------------------------------------------------------------------------
__global__ void wtrans(const float* __restrict__ src, short* __restrict__ dst,
                       int K, int N, int Npad, int perL_dst)
{
    const int idx = blockIdx.x * 256 + threadIdx.x;
    const int l = idx / perL_dst;
    const int r = idx - l * perL_dst;
    const unsigned n = (unsigned)r / (unsigned)K;
    const unsigned k = (unsigned)r - n * (unsigned)K;
    float v = (n < (unsigned)N) ? src[(size_t)l * K * N + k * N + n] : 0.f;
    dst[idx] = f2bf(v);
}

// dtWt[l][d][r] = dtW[l][r][d]  (fp32 transpose, per-thread columns)
__global__ void prep_dtWt(const float* __restrict__ dtW, float* __restrict__ dtWt)
{
    const int idx = blockIdx.x * 256 + threadIdx.x;   // NL*DI*DR
    const int l = idx / (DI * DR);
    const int r0 = idx - l * (DI * DR);
    const int d = r0 / DR, rr = r0 - d * DR;
    dtWt[idx] = dtW[(size_t)l * DR * DI + rr * DI + d];
}

// negA2[l][d][s] = -log2(e) * exp(A_log[l][d][s])
__global__ void prep_A2(const float* __restrict__ A_log, float* __restrict__ negA2)
{
    const int i = blockIdx.x * 256 + threadIdx.x;     // NL*DI*DS
    negA2[i] = -LOG2E * fexp2(LOG2E * A_log[i]);
}

// xb = bf16(x), elementwise
__global__ void cvt_bf16(const float* __restrict__ src, short* __restrict__ dst)
{
    const int i = blockIdx.x * 256 + threadIdx.x;
    dst[i] = f2bf(src[i]);
}

// ---------------------------------------------------------------------------
// MFMA bf16 GEMM.  A[M,K] bf16, Bt[Npad][K] bf16.  Tile 128x64, 4 waves.
// 1-D grid with XCD-aware swizzle: xcd = bid&7 owns NYB/8 row panels and
// walks all NXB column blocks of a panel before advancing (A panel stays in
// that XCD's L2).
// EP 0: split write at col 512 -> C | C1    [in-proj]
// EP 1: C[row*ldc+col] = acc for col < Ncut [x-proj]
// EP 2: C[row*ldc+col] += acc               [out-proj]
// EP 3: C[row*ldc+col] = acc + bias[col]    [first-proj]
// ---------------------------------------------------------------------------
template <int EP>
__global__ void gemm_mfma(const short* __restrict__ A, const short* __restrict__ Bt,
                          float* __restrict__ C, float* __restrict__ C1,
                          const float* __restrict__ bias,
                          int K, int lda, int ldc, int Ncut, int NXB, int NYB)
{
    __shared__ short smem[7680];          // A: 128*40, B: 64*40 (shorts)
    const int bid = blockIdx.x;
    const int xcd = bid & 7, j = bid >> 3;
    const int by = xcd * (NYB >> 3) + j / NXB;
    const int bx = j - (j / NXB) * NXB;
    const int m0 = by * 128;
    const int n0 = bx * 64;

    const int tid = threadIdx.x;
    const int lane = tid & 63, w = tid >> 6;
    const int wr = w >> 1, wc = w & 1;
    const int lr = lane & 15, lk = lane >> 4;

    f32x4 acc[4][2] = {};
    for (int k0 = 0; k0 < K; k0 += 32) {
        __syncthreads();
        // stage A: 128 rows x 32 k (bf16 direct)
#pragma unroll
        for (int i = 0; i < 2; ++i) {
            int c = tid + i * 256;
            int row = c >> 2, seg = c & 3;
            bf16x8 v = *(const bf16x8*)(A + (size_t)(m0 + row) * lda + k0 + seg * 8);
            *(bf16x8*)(&smem[row * 40 + seg * 8]) = v;
        }
        // stage B: 64 rows x 32 k
        {
            int row = tid >> 2, seg = tid & 3;
            bf16x8 v = *(const bf16x8*)(Bt + (size_t)(n0 + row) * K + k0 + seg * 8);
            *(bf16x8*)(&smem[5120 + row * 40 + seg * 8]) = v;
        }
        __syncthreads();
        bf16x8 af[4], bfr[2];
#pragma unroll
        for (int m = 0; m < 4; ++m)
            af[m] = *(const bf16x8*)(&smem[(wr * 64 + m * 16 + lr) * 40 + lk * 8]);
#pragma unroll
        for (int n = 0; n < 2; ++n)
            bfr[n] = *(const bf16x8*)(&smem[5120 + (wc * 32 + n * 16 + lr) * 40 + lk * 8]);
#pragma unroll
        for (int m = 0; m < 4; ++m)
#pragma unroll
            for (int n = 0; n < 2; ++n)
                acc[m][n] = __builtin_amdgcn_mfma_f32_16x16x32_bf16(af[m], bfr[n], acc[m][n], 0, 0, 0);
    }
#pragma unroll
    for (int m = 0; m < 4; ++m) {
#pragma unroll
        for (int n = 0; n < 2; ++n) {
            const int col = n0 + wc * 32 + n * 16 + lr;
#pragma unroll
            for (int j2 = 0; j2 < 4; ++j2) {
                const int row = m0 + wr * 64 + m * 16 + lk * 4 + j2;
                const float v = acc[m][n][j2];
                if (EP == 0) {
                    if (col < DI) C[(size_t)row * DI + col] = v;
                    else          C1[(size_t)row * DI + col - DI] = v;
                } else if (EP == 1) {
                    if (col < Ncut) C[(size_t)row * ldc + col] = v;
                } else if (EP == 2) {
                    C[(size_t)row * ldc + col] += v;
                } else {
                    C[(size_t)row * ldc + col] = v + bias[col];
                }
            }
        }
    }
}

// ---------------------------------------------------------------------------
// LayerNorm over last dim (256) -> bf16 output.
// ---------------------------------------------------------------------------
__global__ void layernorm_kernel(const float* __restrict__ x,
                                 const float* __restrict__ w,
                                 const float* __restrict__ b,
                                 short* __restrict__ out)
{
    const int row = blockIdx.x;
    const int t = threadIdx.x;
    const int wid = t >> 6, lane = t & 63;
    __shared__ float red[4];

    float v = x[row * DM + t];
    float s = v;
#pragma unroll
    for (int o = 32; o >= 1; o >>= 1) s += __shfl_xor(s, o);
    if (lane == 0) red[wid] = s;
    __syncthreads();
    float mu = (red[0] + red[1] + red[2] + red[3]) * (1.f / DM);
    __syncthreads();

    float d = v - mu;
    float q = d * d;
#pragma unroll
    for (int o = 32; o >= 1; o >>= 1) q += __shfl_xor(q, o);
    if (lane == 0) red[wid] = q;
    __syncthreads();
    float var = (red[0] + red[1] + red[2] + red[3]) * (1.f / DM);

    out[row * DM + t] = f2bf(d * (1.f / sqrtf(var + 1e-5f)) * w[t] + b[t]);
}

// ---------------------------------------------------------------------------
// Depthwise causal conv (width 4) + bias + SiLU; writes fp32 (scan) + bf16
// (x-proj GEMM A).
// ---------------------------------------------------------------------------
__global__ void conv_silu_kernel(const float* __restrict__ xs,
                                 const float* __restrict__ W,   // [4, DI]
                                 const float* __restrict__ Bc,  // [DI]
                                 float* __restrict__ xc, short* __restrict__ xcb)
{
    const int idx = blockIdx.x * blockDim.x + threadIdx.x;
    const int c = idx & (DI - 1);
    const int bt = idx >> 9;
    const int t = bt & (T - 1);
    float acc = Bc[c];
#pragma unroll
    for (int k = 0; k < 4; ++k) {
        int tt = t + k - 3;
        if (tt >= 0) acc += xs[(bt + k - 3) * DI + c] * W[k * DI + c];
    }
    float v = siluf(acc);
    xc[idx] = v;
    xcb[idx] = f2bf(v);
}

// ---------------------------------------------------------------------------
// Chunked selective scan, lane-per-d, dt-projection fused (softplus(
// xd[:, :16] @ dtW + dtB) computed in-register from LDS-staged xd slice).
// ---------------------------------------------------------------------------
__global__ void scan_pass1(const float* __restrict__ xd,
                           const float* __restrict__ xc,
                           const float* __restrict__ negA2, // [DI*DS] slice
                           const float* __restrict__ dtWt,  // [DI*DR] slice
                           const float* __restrict__ dtB,   // [DI] slice
                           float* __restrict__ P, float* __restrict__ S)
{
    __shared__ float lds[CL][32];   // [t][0:16]=dt_r, [16:32]=Bm
    const int d = blockIdx.x * 256 + threadIdx.x;
    const int c = blockIdx.y;
    const int b = blockIdx.z;
    const int row0 = b * T + c * CL;

    {
        int t = threadIdx.x >> 3, seg = threadIdx.x & 7;
        *(f32x4*)&lds[t][seg * 4] =
            *(const f32x4*)(xd + (size_t)(row0 + t) * XD + seg * 4);
    }
    float A2[DS], h[DS], wcol[DR];
#pragma unroll
    for (int q = 0; q < 4; ++q) {
        *(f32x4*)&A2[q * 4]   = *(const f32x4*)(negA2 + d * DS + q * 4);
        *(f32x4*)&wcol[q * 4] = *(const f32x4*)(dtWt + d * DR + q * 4);
    }
#pragma unroll
    for (int s = 0; s < DS; ++s) h[s] = 0.f;
    const float dtBd = dtB[d];
    float sdt = 0.f;
    __syncthreads();

    for (int t = 0; t < CL; ++t) {
        float xcv = xc[(size_t)(row0 + t) * DI + d];
        float acc = dtBd;
#pragma unroll
        for (int r = 0; r < DR; ++r) acc += lds[t][r] * wcol[r];
        float dtv = softplusf(acc);
        float dx = dtv * xcv;
        sdt += dtv;
#pragma unroll
        for (int s = 0; s < DS; ++s) {
            float a = fexp2(dtv * A2[s]);
            h[s] = a * h[s] + dx * lds[t][16 + s];
        }
    }
    const size_t base = (size_t)c * SCN + ((size_t)b * DI + d) * DS;
#pragma unroll
    for (int q = 0; q < 4; ++q) {
        f32x4 hp, pp;
#pragma unroll
        for (int j = 0; j < 4; ++j) {
            hp[j] = h[q * 4 + j];
            pp[j] = fexp2(A2[q * 4 + j] * sdt);
        }
        *(f32x4*)(S + base + q * 4) = hp;
        *(f32x4*)(P + base + q * 4) = pp;
    }
}

__global__ void scan_combine(float* __restrict__ P, const float* __restrict__ S)
{
    const int idx3 = blockIdx.x * blockDim.x + threadIdx.x;
    float h = 0.f;
    for (int c = 0; c < NC; ++c) {
        float pc = P[c * SCN + idx3];
        float sc = S[c * SCN + idx3];
        P[c * SCN + idx3] = h;
        h = pc * h + sc;
    }
}

__global__ void scan_pass2(const float* __restrict__ xd,
                           const float* __restrict__ xc,
                           const float* __restrict__ negA2,
                           const float* __restrict__ dtWt,
                           const float* __restrict__ dtB,
                           const float* __restrict__ Dv,
                           const float* __restrict__ H,   // [NC][SCN] (=P)
                           const float* __restrict__ z,
                           short* __restrict__ yb)        // bf16 out (gated)
{
    __shared__ float lds[CL][48];   // [t][0:16]=dt_r, [16:32]=Bm, [32:48]=Cm
    const int d = blockIdx.x * 256 + threadIdx.x;
    const int c = blockIdx.y;
    const int b = blockIdx.z;
    const int row0 = b * T + c * CL;

    for (int c0 = threadIdx.x; c0 < CL * 12; c0 += 256) {
        int t = c0 / 12, seg = c0 - t * 12;
        *(f32x4*)&lds[t][seg * 4] =
            *(const f32x4*)(xd + (size_t)(row0 + t) * XD + seg * 4);
    }
    float A2[DS], h[DS], wcol[DR];
#pragma unroll
    for (int q = 0; q < 4; ++q) {
        *(f32x4*)&A2[q * 4]   = *(const f32x4*)(negA2 + d * DS + q * 4);
        *(f32x4*)&wcol[q * 4] = *(const f32x4*)(dtWt + d * DR + q * 4);
    }
    const size_t base = (size_t)c * SCN + ((size_t)b * DI + d) * DS;
#pragma unroll
    for (int q = 0; q < 4; ++q)
        *(f32x4*)&h[q * 4] = *(const f32x4*)(H + base + q * 4);
    const float dtBd = dtB[d];
    const float Dd = Dv[d];
    __syncthreads();

    for (int t = 0; t < CL; ++t) {
        const size_t row = (size_t)(row0 + t);
        float xcv = xc[row * DI + d];
        float zv  = z[row * DI + d];
        float acc = dtBd;
#pragma unroll
        for (int r = 0; r < DR; ++r) acc += lds[t][r] * wcol[r];
        float dtv = softplusf(acc);
        float dx = dtv * xcv;
        float acc0 = 0.f, acc1 = 0.f, acc2 = 0.f, acc3 = 0.f;
#pragma unroll
        for (int s = 0; s < DS; s += 4) {
            float a0 = fexp2(dtv * A2[s + 0]);
            h[s + 0] = a0 * h[s + 0] + dx * lds[t][16 + s + 0];
            acc0 += h[s + 0] * lds[t][32 + s + 0];
            float a1 = fexp2(dtv * A2[s + 1]);
            h[s + 1] = a1 * h[s + 1] + dx * lds[t][16 + s + 1];
            acc1 += h[s + 1] * lds[t][32 + s + 1];
            float a2 = fexp2(dtv * A2[s + 2]);
            h[s + 2] = a2 * h[s + 2] + dx * lds[t][16 + s + 2];
            acc2 += h[s + 2] * lds[t][32 + s + 2];
            float a3 = fexp2(dtv * A2[s + 3]);
            h[s + 3] = a3 * h[s + 3] + dx * lds[t][16 + s + 3];
            acc3 += h[s + 3] * lds[t][32 + s + 3];
        }
        float yv = (acc0 + acc1) + (acc2 + acc3);
        yb[row * DI + d] = f2bf((yv + xcv * Dd) * siluf(zv));
    }
}

// ---------------------------------------------------------------------------
// Head: final LN on last token, gelu(last@h1W+h1b) @ h2W + h2b.
// ---------------------------------------------------------------------------
__global__ void head_kernel(const float* __restrict__ h,
                            const float* __restrict__ fw, const float* __restrict__ fb,
                            const float* __restrict__ h1W, const float* __restrict__ h1b,
                            const float* __restrict__ h2W, const float* __restrict__ h2b,
                            float* __restrict__ out)
{
    const int bi = blockIdx.x;
    const int t = threadIdx.x;
    const int wid = t >> 6, lane = t & 63;
    __shared__ float red[4];
    __shared__ float ln[DM];
    __shared__ float hid[DM / 2];

    const float* row = h + ((bi + 1) * T - 1) * DM;
    float v = row[t];
    float s = v;
#pragma unroll
    for (int o = 32; o >= 1; o >>= 1) s += __shfl_xor(s, o);
    if (lane == 0) red[wid] = s;
    __syncthreads();
    float mu = (red[0] + red[1] + red[2] + red[3]) * (1.f / DM);
    __syncthreads();
    float d = v - mu;
    float q = d * d;
#pragma unroll
    for (int o = 32; o >= 1; o >>= 1) q += __shfl_xor(q, o);
    if (lane == 0) red[wid] = q;
    __syncthreads();
    float var = (red[0] + red[1] + red[2] + red[3]) * (1.f / DM);
    ln[t] = d * (1.f / sqrtf(var + 1e-5f)) * fw[t] + fb[t];
    __syncthreads();

    if (t < DM / 2) {
        float acc = h1b[t];
        for (int k = 0; k < DM; ++k) acc += ln[k] * h1W[k * (DM / 2) + t];
        float x3 = acc * acc * acc;
        hid[t] = 0.5f * acc * (1.f + tanhf(0.7978845608028654f * (acc + 0.044715f * x3)));
    }
    __syncthreads();
    if (t < 3) {
        float acc = h2b[t];
        for (int k = 0; k < DM / 2; ++k) acc += hid[k] * h2W[k * 3 + t];
        out[bi * 3 + t] = acc;
    }
}

} // namespace

extern "C" void kernel_launch(void* const* d_in, const int* in_sizes, int n_in,
                              void* d_out, int out_size, void* d_ws, size_t ws_size,
                              hipStream_t stream)
{
    (void)in_sizes; (void)n_in; (void)out_size; (void)ws_size;
    const float* x     = (const float*)d_in[0];
    const float* in_w  = (const float*)d_in[1];
    const float* in_b  = (const float*)d_in[2];
    const float* ln_w  = (const float*)d_in[3];
    const float* ln_b  = (const float*)d_in[4];
    const float* inW   = (const float*)d_in[5];
    const float* convW = (const float*)d_in[6];
    const float* convB = (const float*)d_in[7];
    const float* xpW   = (const float*)d_in[8];
    const float* dtW   = (const float*)d_in[9];
    const float* A_log = (const float*)d_in[10];
    const float* Dv    = (const float*)d_in[11];
    const float* outW  = (const float*)d_in[12];
    const float* fln_w = (const float*)d_in[13];
    const float* fln_b = (const float*)d_in[14];
    const float* h1W   = (const float*)d_in[15];
    const float* h1b   = (const float*)d_in[16];
    const float* h2W   = (const float*)d_in[17];
    const float* h2b   = (const float*)d_in[18];
    const float* dtB   = (const float*)d_in[19];
    float* out = (float*)d_out;

    float* w = (float*)d_ws;
    float* hbuf  = w;  w += ROWS * DM;
    float* xs    = w;  w += ROWS * DI;
    float* z     = w;  w += ROWS * DI;
    float* xc    = w;  w += ROWS * DI;
    float* xd    = w;  w += ROWS * XD;
    float* P     = w;  w += SCN;          // P/S are [NC][SCN]
    w += (size_t)SCN * (NC - 1);
    float* S     = w;  w += SCN;
    w += (size_t)SCN * (NC - 1);
    float* negA2 = w;  w += NL * DI * DS;
    float* dtWt  = w;  w += NL * DI * DR;
    short* xlnb  = (short*)w;
    short* xb    = xlnb + (size_t)ROWS * DM;
    short* xcb   = xb + (size_t)ROWS * NF;
    short* yb    = xcb + (size_t)ROWS * DI;
    short* inWt  = yb + (size_t)ROWS * DI;        // [4][1024][256]
    short* xpWt  = inWt + (size_t)NL * 1024 * DM; // [4][64][512]
    short* outWt = xpWt + (size_t)NL * 64 * DI;   // [4][256][512]
    short* inwT  = outWt + (size_t)NL * DM * DI;  // [256][32]

    // --- prep (weights to bf16/N-major; constants) ---
    wtrans<<<NL * 1024 * DM / 256, 256, 0, stream>>>(inW, inWt, DM, 1024, 1024, 1024 * DM);
    wtrans<<<NL * 64 * DI / 256, 256, 0, stream>>>(xpW, xpWt, DI, XD, 64, 64 * DI);
    wtrans<<<NL * DM * DI / 256, 256, 0, stream>>>(outW, outWt, DI, DM, DM, DM * DI);
    wtrans<<<DM * NF / 256, 256, 0, stream>>>(in_w, inwT, NF, DM, DM, DM * NF);
    prep_dtWt<<<NL * DI * DR / 256, 256, 0, stream>>>(dtW, dtWt);
    prep_A2<<<NL * DI * DS / 256, 256, 0, stream>>>(A_log, negA2);
    cvt_bf16<<<ROWS * NF / 256, 256, 0, stream>>>(x, xb);

    // h = x @ in_w + in_b  (MFMA)
    gemm_mfma<3><<<(DM / 64) * (ROWS / 128), 256, 0, stream>>>(
        xb, inwT, hbuf, nullptr, in_b, NF, NF, DM, 0, DM / 64, ROWS / 128);

    for (int i = 0; i < NL; ++i) {
        layernorm_kernel<<<ROWS, DM, 0, stream>>>(hbuf, ln_w + i * DM, ln_b + i * DM, xlnb);

        gemm_mfma<0><<<(1024 / 64) * (ROWS / 128), 256, 0, stream>>>(
            xlnb, inWt + (size_t)i * 1024 * DM, xs, z, nullptr,
            DM, DM, 0, 0, 1024 / 64, ROWS / 128);

        conv_silu_kernel<<<ROWS * DI / 256, 256, 0, stream>>>(
            xs, convW + i * 4 * DI, convB + i * DI, xc, xcb);

        gemm_mfma<1><<<1 * (ROWS / 128), 256, 0, stream>>>(
            xcb, xpWt + (size_t)i * 64 * DI, xd, nullptr, nullptr,
            DI, DI, XD, XD, 1, ROWS / 128);

        scan_pass1<<<dim3(DI / 256, NC, NB), 256, 0, stream>>>(
            xd, xc, negA2 + i * DI * DS, dtWt + i * DI * DR, dtB + i * DI, P, S);
        scan_combine<<<SCN / 256, 256, 0, stream>>>(P, S);
        scan_pass2<<<dim3(DI / 256, NC, NB), 256, 0, stream>>>(
            xd, xc, negA2 + i * DI * DS, dtWt + i * DI * DR, dtB + i * DI,
            Dv + i * DI, P, z, yb);

        gemm_mfma<2><<<(DM / 64) * (ROWS / 128), 256, 0, stream>>>(
            yb, outWt + (size_t)i * DM * DI, hbuf, nullptr, nullptr,
            DI, DI, DM, 0, DM / 64, ROWS / 128);
    }

    head_kernel<<<NB, DM, 0, stream>>>(hbuf, fln_w, fln_b, h1W, h1b, h2W, h2b, out);
}

// Round 7
// 644.532 us; speedup vs baseline: 11.7925x; 1.2658x over previous
//
#include <hip/hip_runtime.h>
#include <math.h>

namespace {

constexpr int NL = 4;      // layers
constexpr int DM = 256;    // d_model
constexpr int DI = 512;    // d_inner
constexpr int DS = 16;     // d_state
constexpr int DR = 16;     // dt_rank
constexpr int NF = 32;     // n_features
constexpr int NB = 8;      // batch
constexpr int T  = 2048;   // seq
constexpr int ROWS = NB * T;       // 16384
constexpr int XD = DR + 2 * DS;    // 48
constexpr int NC = 64;             // scan chunks
constexpr int CL = T / NC;         // 32 steps per chunk
constexpr int SCN = NB * DI * DS;  // 65536 scan states

constexpr float LOG2E = 1.44269504088896341f;
constexpr float LN2   = 0.69314718055994531f;

typedef __attribute__((ext_vector_type(4))) float f32x4;
typedef __attribute__((ext_vector_type(8))) short bf16x8;
typedef __attribute__((ext_vector_type(4))) short s16x4;

__device__ __forceinline__ float fexp2(float x) { return __builtin_amdgcn_exp2f(x); }
__device__ __forceinline__ float frcp(float x)  { return __builtin_amdgcn_rcpf(x); }
__device__ __forceinline__ float flog2(float x) { return __builtin_amdgcn_logf(x); }

__device__ __forceinline__ float siluf(float x) {
    return x * frcp(1.f + fexp2(-LOG2E * x));
}
__device__ __forceinline__ float softplusf(float x) {
    return fmaxf(x, 0.f) + LN2 * flog2(1.f + fexp2(-LOG2E * fabsf(x)));
}
__device__ __forceinline__ short f2bf(float f) {   // RNE float->bf16
    union { float f; unsigned u; } c; c.f = f;
    unsigned r = (c.u + 0x7FFFu + ((c.u >> 16) & 1u)) >> 16;
    return (short)r;
}
__device__ __forceinline__ float bf2f(short s) {
    union { unsigned u; float f; } c; c.u = ((unsigned)(unsigned short)s) << 16;
    return c.f;
}
// a[s] = g^(s+1), s=0..15, depth-4 multiply tree
__device__ __forceinline__ void powers16(float g, float* a) {
    float g2 = g * g, g4 = g2 * g2, g8 = g4 * g4;
    a[0] = g;        a[1] = g2;       a[2] = g * g2;   a[3] = g4;
    a[4] = g * g4;   a[5] = g2 * g4;  a[6] = a[2] * g4; a[7] = g8;
    a[8] = g * g8;   a[9] = g2 * g8;  a[10] = a[2] * g8; a[11] = g4 * g8;
    a[12] = a[4] * g8; a[13] = a[5] * g8; a[14] = a[6] * g8; a[15] = g8 * g8;
}

// ---------------------------------------------------------------------------
// Weight prep: dst[l][Npad][K] (bf16) = transpose(src[l][K][N]); pad n>=N.
// ---------------------------------------------------------------------------
__global__ void wtrans(const float* __restrict__ src, short* __restrict__ dst,
                       int K, int N, int Npad, int perL_dst)
{
    const int idx = blockIdx.x * 256 + threadIdx.x;
    const int l = idx / perL_dst;
    const int r = idx - l * perL_dst;
    const unsigned n = (unsigned)r / (unsigned)K;
    const unsigned k = (unsigned)r - n * (unsigned)K;
    float v = (n < (unsigned)N) ? src[(size_t)l * K * N + k * N + n] : 0.f;
    dst[idx] = f2bf(v);
}

// dtWt[l][d][r] = dtW[l][r][d]
__global__ void prep_dtWt(const float* __restrict__ dtW, float* __restrict__ dtWt)
{
    const int idx = blockIdx.x * 256 + threadIdx.x;   // NL*DI*DR
    const int l = idx / (DI * DR);
    const int r0 = idx - l * (DI * DR);
    const int d = r0 / DR, rr = r0 - d * DR;
    dtWt[idx] = dtW[(size_t)l * DR * DI + rr * DI + d];
}

// negA2[l][d][s] = -log2(e) * exp(A_log[l][d][s])
__global__ void prep_A2(const float* __restrict__ A_log, float* __restrict__ negA2)
{
    const int i = blockIdx.x * 256 + threadIdx.x;     // NL*DI*DS
    negA2[i] = -LOG2E * fexp2(LOG2E * A_log[i]);
}

__global__ void cvt_bf16(const float* __restrict__ src, short* __restrict__ dst)
{
    const int i = blockIdx.x * 256 + threadIdx.x;
    dst[i] = f2bf(src[i]);
}

// ---------------------------------------------------------------------------
// MFMA bf16 GEMM.  A[M,K] bf16, Bt[Npad][K] bf16.  Tile 128x64, 4 waves.
// XCD-aware 1-D swizzle (xcd owns contiguous row panels, walks all col blocks).
// EP 0: split: col<512 -> bf16 Cs0;  col>=512 -> bf16 Cs1 = silu(acc)  [in-proj]
// EP 1: fp32 C[row*ldc+col] = acc for col < Ncut                       [x-proj]
// EP 2: fp32 C[row*ldc+col] += acc                                     [out-proj]
// EP 3: fp32 C[row*ldc+col] = acc + bias[col]                          [first]
// ---------------------------------------------------------------------------
template <int EP>
__global__ void gemm_mfma(const short* __restrict__ A, const short* __restrict__ Bt,
                          float* __restrict__ C, short* __restrict__ Cs0,
                          short* __restrict__ Cs1, const float* __restrict__ bias,
                          int K, int lda, int ldc, int Ncut, int NXB, int NYB)
{
    __shared__ short smem[7680];          // A: 128*40, B: 64*40 (shorts)
    const int bid = blockIdx.x;
    const int xcd = bid & 7, j = bid >> 3;
    const int by = xcd * (NYB >> 3) + j / NXB;
    const int bx = j - (j / NXB) * NXB;
    const int m0 = by * 128;
    const int n0 = bx * 64;

    const int tid = threadIdx.x;
    const int lane = tid & 63, w = tid >> 6;
    const int wr = w >> 1, wc = w & 1;
    const int lr = lane & 15, lk = lane >> 4;

    f32x4 acc[4][2] = {};
    for (int k0 = 0; k0 < K; k0 += 32) {
        __syncthreads();
#pragma unroll
        for (int i = 0; i < 2; ++i) {
            int c = tid + i * 256;
            int row = c >> 2, seg = c & 3;
            bf16x8 v = *(const bf16x8*)(A + (size_t)(m0 + row) * lda + k0 + seg * 8);
            *(bf16x8*)(&smem[row * 40 + seg * 8]) = v;
        }
        {
            int row = tid >> 2, seg = tid & 3;
            bf16x8 v = *(const bf16x8*)(Bt + (size_t)(n0 + row) * K + k0 + seg * 8);
            *(bf16x8*)(&smem[5120 + row * 40 + seg * 8]) = v;
        }
        __syncthreads();
        bf16x8 af[4], bfr[2];
#pragma unroll
        for (int m = 0; m < 4; ++m)
            af[m] = *(const bf16x8*)(&smem[(wr * 64 + m * 16 + lr) * 40 + lk * 8]);
#pragma unroll
        for (int n = 0; n < 2; ++n)
            bfr[n] = *(const bf16x8*)(&smem[5120 + (wc * 32 + n * 16 + lr) * 40 + lk * 8]);
#pragma unroll
        for (int m = 0; m < 4; ++m)
#pragma unroll
            for (int n = 0; n < 2; ++n)
                acc[m][n] = __builtin_amdgcn_mfma_f32_16x16x32_bf16(af[m], bfr[n], acc[m][n], 0, 0, 0);
    }
#pragma unroll
    for (int m = 0; m < 4; ++m) {
#pragma unroll
        for (int n = 0; n < 2; ++n) {
            const int col = n0 + wc * 32 + n * 16 + lr;
#pragma unroll
            for (int j2 = 0; j2 < 4; ++j2) {
                const int row = m0 + wr * 64 + m * 16 + lk * 4 + j2;
                const float v = acc[m][n][j2];
                if (EP == 0) {
                    if (col < DI) Cs0[(size_t)row * DI + col] = f2bf(v);
                    else          Cs1[(size_t)row * DI + col - DI] = f2bf(siluf(v));
                } else if (EP == 1) {
                    if (col < Ncut) C[(size_t)row * ldc + col] = v;
                } else if (EP == 2) {
                    C[(size_t)row * ldc + col] += v;
                } else {
                    C[(size_t)row * ldc + col] = v + bias[col];
                }
            }
        }
    }
}

// ---------------------------------------------------------------------------
// LayerNorm over last dim (256) -> bf16 output.
// ---------------------------------------------------------------------------
__global__ void layernorm_kernel(const float* __restrict__ x,
                                 const float* __restrict__ w,
                                 const float* __restrict__ b,
                                 short* __restrict__ out)
{
    const int row = blockIdx.x;
    const int t = threadIdx.x;
    const int wid = t >> 6, lane = t & 63;
    __shared__ float red[4];

    float v = x[row * DM + t];
    float s = v;
#pragma unroll
    for (int o = 32; o >= 1; o >>= 1) s += __shfl_xor(s, o);
    if (lane == 0) red[wid] = s;
    __syncthreads();
    float mu = (red[0] + red[1] + red[2] + red[3]) * (1.f / DM);
    __syncthreads();

    float d = v - mu;
    float q = d * d;
#pragma unroll
    for (int o = 32; o >= 1; o >>= 1) q += __shfl_xor(q, o);
    if (lane == 0) red[wid] = q;
    __syncthreads();
    float var = (red[0] + red[1] + red[2] + red[3]) * (1.f / DM);

    out[row * DM + t] = f2bf(d * (1.f / sqrtf(var + 1e-5f)) * w[t] + b[t]);
}

// ---------------------------------------------------------------------------
// Depthwise causal conv (width 4) + bias + SiLU.  bf16 in/out, 4 chans/thread.
// ---------------------------------------------------------------------------
__global__ void conv_silu_kernel(const short* __restrict__ xsb,
                                 const float* __restrict__ W,   // [4, DI]
                                 const float* __restrict__ Bc,  // [DI]
                                 short* __restrict__ xcb)
{
    const int idx = blockIdx.x * 256 + threadIdx.x;   // over ROWS*DI/4
    const int c4 = idx & (DI / 4 - 1);
    const int bt = idx >> 7;
    const int t = bt & (T - 1);
    const int c = c4 * 4;
    f32x4 acc = *(const f32x4*)(Bc + c);
#pragma unroll
    for (int k = 0; k < 4; ++k) {
        int tt = t + k - 3;
        if (tt >= 0) {
            s16x4 v = *(const s16x4*)(xsb + (size_t)(bt + k - 3) * DI + c);
            f32x4 wv = *(const f32x4*)(W + k * DI + c);
#pragma unroll
            for (int q = 0; q < 4; ++q) acc[q] += bf2f(v[q]) * wv[q];
        }
    }
    s16x4 o;
#pragma unroll
    for (int q = 0; q < 4; ++q) o[q] = f2bf(siluf(acc[q]));
    *(s16x4*)(xcb + (size_t)idx * 4) = o;
}

// ---------------------------------------------------------------------------
// Chunked selective scan, lane-per-d; dt-projection fused; structured-A
// fast path (a[s] = g^(s+1)) with generic 16-exp fallback.
// ---------------------------------------------------------------------------
__global__ void scan_pass1(const float* __restrict__ xd,
                           const short* __restrict__ xcb,
                           const float* __restrict__ negA2, // [DI*DS] slice
                           const float* __restrict__ dtWt,  // [DI*DR] slice
                           const float* __restrict__ dtB,   // [DI] slice
                           float* __restrict__ P, float* __restrict__ S)
{
    __shared__ float lds[CL][32];   // [t][0:16]=dt_r, [16:32]=Bm
    const int d = blockIdx.x * 256 + threadIdx.x;
    const int c = blockIdx.y;
    const int b = blockIdx.z;
    const int row0 = b * T + c * CL;

    {
        int t = threadIdx.x >> 3, seg = threadIdx.x & 7;
        *(f32x4*)&lds[t][seg * 4] =
            *(const f32x4*)(xd + (size_t)(row0 + t) * XD + seg * 4);
    }
    float A2[DS], h[DS], wcol[DR];
#pragma unroll
    for (int q = 0; q < 4; ++q) {
        *(f32x4*)&A2[q * 4]   = *(const f32x4*)(negA2 + d * DS + q * 4);
        *(f32x4*)&wcol[q * 4] = *(const f32x4*)(dtWt + d * DR + q * 4);
    }
    bool fastb = true;
#pragma unroll
    for (int s = 1; s < DS; ++s)
        fastb = fastb && (fabsf(A2[s] - A2[0] * (float)(s + 1)) <= 1e-4f * fabsf(A2[s]));
    const bool fast = __all(fastb);
#pragma unroll
    for (int s = 0; s < DS; ++s) h[s] = 0.f;
    const float dtBd = dtB[d];
    float sdt = 0.f;
    __syncthreads();

    for (int t = 0; t < CL; ++t) {
        float xcv = bf2f(xcb[(size_t)(row0 + t) * DI + d]);
        float accd = dtBd;
#pragma unroll
        for (int q = 0; q < 4; ++q) {
            f32x4 xr = *(const f32x4*)&lds[t][q * 4];
            accd += xr[0] * wcol[q * 4] + xr[1] * wcol[q * 4 + 1]
                  + xr[2] * wcol[q * 4 + 2] + xr[3] * wcol[q * 4 + 3];
        }
        float dtv = softplusf(accd);
        float dx = dtv * xcv;
        sdt += dtv;
        float a[DS];
        if (fast) powers16(fexp2(dtv * A2[0]), a);
        else {
#pragma unroll
            for (int s = 0; s < DS; ++s) a[s] = fexp2(dtv * A2[s]);
        }
#pragma unroll
        for (int q = 0; q < 4; ++q) {
            f32x4 Bv = *(const f32x4*)&lds[t][16 + q * 4];
#pragma unroll
            for (int s = 0; s < 4; ++s)
                h[q * 4 + s] = a[q * 4 + s] * h[q * 4 + s] + dx * Bv[s];
        }
    }
    float pa[DS];
    if (fast) powers16(fexp2(A2[0] * sdt), pa);
    else {
#pragma unroll
        for (int s = 0; s < DS; ++s) pa[s] = fexp2(A2[s] * sdt);
    }
    const size_t base = (size_t)c * SCN + ((size_t)b * DI + d) * DS;
#pragma unroll
    for (int q = 0; q < 4; ++q) {
        *(f32x4*)(S + base + q * 4) = *(f32x4*)&h[q * 4];
        *(f32x4*)(P + base + q * 4) = *(f32x4*)&pa[q * 4];
    }
}

__global__ void scan_combine(float* __restrict__ P, const float* __restrict__ S)
{
    const int idx3 = blockIdx.x * blockDim.x + threadIdx.x;
    float h = 0.f;
    for (int c = 0; c < NC; ++c) {
        float pc = P[c * SCN + idx3];
        float sc = S[c * SCN + idx3];
        P[c * SCN + idx3] = h;
        h = pc * h + sc;
    }
}

__global__ void scan_pass2(const float* __restrict__ xd,
                           const short* __restrict__ xcb,
                           const float* __restrict__ negA2,
                           const float* __restrict__ dtWt,
                           const float* __restrict__ dtB,
                           const float* __restrict__ Dv,
                           const float* __restrict__ H,    // [NC][SCN] (=P)
                           const short* __restrict__ zgb,  // bf16 silu(z)
                           short* __restrict__ yb)         // bf16 out (gated)
{
    __shared__ float lds[CL][48];   // [t][0:16]=dt_r, [16:32]=Bm, [32:48]=Cm
    const int d = blockIdx.x * 256 + threadIdx.x;
    const int c = blockIdx.y;
    const int b = blockIdx.z;
    const int row0 = b * T + c * CL;

    for (int c0 = threadIdx.x; c0 < CL * 12; c0 += 256) {
        int t = c0 / 12, seg = c0 - t * 12;
        *(f32x4*)&lds[t][seg * 4] =
            *(const f32x4*)(xd + (size_t)(row0 + t) * XD + seg * 4);
    }
    float A2[DS], h[DS], wcol[DR];
#pragma unroll
    for (int q = 0; q < 4; ++q) {
        *(f32x4*)&A2[q * 4]   = *(const f32x4*)(negA2 + d * DS + q * 4);
        *(f32x4*)&wcol[q * 4] = *(const f32x4*)(dtWt + d * DR + q * 4);
    }
    bool fastb = true;
#pragma unroll
    for (int s = 1; s < DS; ++s)
        fastb = fastb && (fabsf(A2[s] - A2[0] * (float)(s + 1)) <= 1e-4f * fabsf(A2[s]));
    const bool fast = __all(fastb);
    const size_t base = (size_t)c * SCN + ((size_t)b * DI + d) * DS;
#pragma unroll
    for (int q = 0; q < 4; ++q)
        *(f32x4*)&h[q * 4] = *(const f32x4*)(H + base + q * 4);
    const float dtBd = dtB[d];
    const float Dd = Dv[d];
    __syncthreads();

    for (int t = 0; t < CL; ++t) {
        const size_t row = (size_t)(row0 + t);
        float xcv = bf2f(xcb[row * DI + d]);
        float zg  = bf2f(zgb[row * DI + d]);
        float accd = dtBd;
#pragma unroll
        for (int q = 0; q < 4; ++q) {
            f32x4 xr = *(const f32x4*)&lds[t][q * 4];
            accd += xr[0] * wcol[q * 4] + xr[1] * wcol[q * 4 + 1]
                  + xr[2] * wcol[q * 4 + 2] + xr[3] * wcol[q * 4 + 3];
        }
        float dtv = softplusf(accd);
        float dx = dtv * xcv;
        float a[DS];
        if (fast) powers16(fexp2(dtv * A2[0]), a);
        else {
#pragma unroll
            for (int s = 0; s < DS; ++s) a[s] = fexp2(dtv * A2[s]);
        }
        float acc0 = 0.f, acc1 = 0.f, acc2 = 0.f, acc3 = 0.f;
#pragma unroll
        for (int q = 0; q < 4; ++q) {
            f32x4 Bv = *(const f32x4*)&lds[t][16 + q * 4];
            f32x4 Cv = *(const f32x4*)&lds[t][32 + q * 4];
            h[q * 4 + 0] = a[q * 4 + 0] * h[q * 4 + 0] + dx * Bv[0];
            acc0 += h[q * 4 + 0] * Cv[0];
            h[q * 4 + 1] = a[q * 4 + 1] * h[q * 4 + 1] + dx * Bv[1];
            acc1 += h[q * 4 + 1] * Cv[1];
            h[q * 4 + 2] = a[q * 4 + 2] * h[q * 4 + 2] + dx * Bv[2];
            acc2 += h[q * 4 + 2] * Cv[2];
            h[q * 4 + 3] = a[q * 4 + 3] * h[q * 4 + 3] + dx * Bv[3];
            acc3 += h[q * 4 + 3] * Cv[3];
        }
        float yv = (acc0 + acc1) + (acc2 + acc3);
        yb[row * DI + d] = f2bf((yv + xcv * Dd) * zg);
    }
}

// ---------------------------------------------------------------------------
// Head: final LN on last token, gelu(last@h1W+h1b) @ h2W + h2b.
// ---------------------------------------------------------------------------
__global__ void head_kernel(const float* __restrict__ h,
                            const float* __restrict__ fw, const float* __restrict__ fb,
                            const float* __restrict__ h1W, const float* __restrict__ h1b,
                            const float* __restrict__ h2W, const float* __restrict__ h2b,
                            float* __restrict__ out)
{
    const int bi = blockIdx.x;
    const int t = threadIdx.x;
    const int wid = t >> 6, lane = t & 63;
    __shared__ float red[4];
    __shared__ float ln[DM];
    __shared__ float hid[DM / 2];

    const float* row = h + ((bi + 1) * T - 1) * DM;
    float v = row[t];
    float s = v;
#pragma unroll
    for (int o = 32; o >= 1; o >>= 1) s += __shfl_xor(s, o);
    if (lane == 0) red[wid] = s;
    __syncthreads();
    float mu = (red[0] + red[1] + red[2] + red[3]) * (1.f / DM);
    __syncthreads();
    float d = v - mu;
    float q = d * d;
#pragma unroll
    for (int o = 32; o >= 1; o >>= 1) q += __shfl_xor(q, o);
    if (lane == 0) red[wid] = q;
    __syncthreads();
    float var = (red[0] + red[1] + red[2] + red[3]) * (1.f / DM);
    ln[t] = d * (1.f / sqrtf(var + 1e-5f)) * fw[t] + fb[t];
    __syncthreads();

    if (t < DM / 2) {
        float acc = h1b[t];
        for (int k = 0; k < DM; ++k) acc += ln[k] * h1W[k * (DM / 2) + t];
        float x3 = acc * acc * acc;
        hid[t] = 0.5f * acc * (1.f + tanhf(0.7978845608028654f * (acc + 0.044715f * x3)));
    }
    __syncthreads();
    if (t < 3) {
        float acc = h2b[t];
        for (int k = 0; k < DM / 2; ++k) acc += hid[k] * h2W[k * 3 + t];
        out[bi * 3 + t] = acc;
    }
}

} // namespace

extern "C" void kernel_launch(void* const* d_in, const int* in_sizes, int n_in,
                              void* d_out, int out_size, void* d_ws, size_t ws_size,
                              hipStream_t stream)
{
    (void)in_sizes; (void)n_in; (void)out_size; (void)ws_size;
    const float* x     = (const float*)d_in[0];
    const float* in_w  = (const float*)d_in[1];
    const float* in_b  = (const float*)d_in[2];
    const float* ln_w  = (const float*)d_in[3];
    const float* ln_b  = (const float*)d_in[4];
    const float* inW   = (const float*)d_in[5];
    const float* convW = (const float*)d_in[6];
    const float* convB = (const float*)d_in[7];
    const float* xpW   = (const float*)d_in[8];
    const float* dtW   = (const float*)d_in[9];
    const float* A_log = (const float*)d_in[10];
    const float* Dv    = (const float*)d_in[11];
    const float* outW  = (const float*)d_in[12];
    const float* fln_w = (const float*)d_in[13];
    const float* fln_b = (const float*)d_in[14];
    const float* h1W   = (const float*)d_in[15];
    const float* h1b   = (const float*)d_in[16];
    const float* h2W   = (const float*)d_in[17];
    const float* h2b   = (const float*)d_in[18];
    const float* dtB   = (const float*)d_in[19];
    float* out = (float*)d_out;

    float* w = (float*)d_ws;
    float* hbuf  = w;  w += ROWS * DM;
    float* xd    = w;  w += ROWS * XD;
    float* P     = w;  w += (size_t)SCN * NC;
    float* S     = w;  w += (size_t)SCN * NC;
    float* negA2 = w;  w += NL * DI * DS;
    float* dtWt  = w;  w += NL * DI * DR;
    short* xlnb  = (short*)w;
    short* xb    = xlnb + (size_t)ROWS * DM;
    short* xsb   = xb   + (size_t)ROWS * NF;
    short* zgb   = xsb  + (size_t)ROWS * DI;
    short* xcb   = zgb  + (size_t)ROWS * DI;
    short* yb    = xcb  + (size_t)ROWS * DI;
    short* inWt  = yb   + (size_t)ROWS * DI;      // [4][1024][256]
    short* xpWt  = inWt + (size_t)NL * 1024 * DM; // [4][64][512]
    short* outWt = xpWt + (size_t)NL * 64 * DI;   // [4][256][512]
    short* inwT  = outWt + (size_t)NL * DM * DI;  // [256][32]

    // --- prep (weights to bf16/N-major; constants) ---
    wtrans<<<NL * 1024 * DM / 256, 256, 0, stream>>>(inW, inWt, DM, 1024, 1024, 1024 * DM);
    wtrans<<<NL * 64 * DI / 256, 256, 0, stream>>>(xpW, xpWt, DI, XD, 64, 64 * DI);
    wtrans<<<NL * DM * DI / 256, 256, 0, stream>>>(outW, outWt, DI, DM, DM, DM * DI);
    wtrans<<<DM * NF / 256, 256, 0, stream>>>(in_w, inwT, NF, DM, DM, DM * NF);
    prep_dtWt<<<NL * DI * DR / 256, 256, 0, stream>>>(dtW, dtWt);
    prep_A2<<<NL * DI * DS / 256, 256, 0, stream>>>(A_log, negA2);
    cvt_bf16<<<ROWS * NF / 256, 256, 0, stream>>>(x, xb);

    // h = x @ in_w + in_b  (MFMA)
    gemm_mfma<3><<<(DM / 64) * (ROWS / 128), 256, 0, stream>>>(
        xb, inwT, hbuf, nullptr, nullptr, in_b, NF, NF, DM, 0, DM / 64, ROWS / 128);

    for (int i = 0; i < NL; ++i) {
        layernorm_kernel<<<ROWS, DM, 0, stream>>>(hbuf, ln_w + i * DM, ln_b + i * DM, xlnb);

        // xz = xln @ inW[i] -> bf16 xs | bf16 silu(z)
        gemm_mfma<0><<<(1024 / 64) * (ROWS / 128), 256, 0, stream>>>(
            xlnb, inWt + (size_t)i * 1024 * DM, nullptr, xsb, zgb, nullptr,
            DM, DM, 0, 0, 1024 / 64, ROWS / 128);

        conv_silu_kernel<<<ROWS * DI / 1024, 256, 0, stream>>>(
            xsb, convW + i * 4 * DI, convB + i * DI, xcb);

        gemm_mfma<1><<<1 * (ROWS / 128), 256, 0, stream>>>(
            xcb, xpWt + (size_t)i * 64 * DI, xd, nullptr, nullptr, nullptr,
            DI, DI, XD, XD, 1, ROWS / 128);

        scan_pass1<<<dim3(DI / 256, NC, NB), 256, 0, stream>>>(
            xd, xcb, negA2 + i * DI * DS, dtWt + i * DI * DR, dtB + i * DI, P, S);
        scan_combine<<<SCN / 256, 256, 0, stream>>>(P, S);
        scan_pass2<<<dim3(DI / 256, NC, NB), 256, 0, stream>>>(
            xd, xcb, negA2 + i * DI * DS, dtWt + i * DI * DR, dtB + i * DI,
            Dv + i * DI, P, zgb, yb);

        gemm_mfma<2><<<(DM / 64) * (ROWS / 128), 256, 0, stream>>>(
            yb, outWt + (size_t)i * DM * DI, hbuf, nullptr, nullptr, nullptr,
            DI, DI, DM, 0, DM / 64, ROWS / 128);
    }

    head_kernel<<<NB, DM, 0, stream>>>(hbuf, fln_w, fln_b, h1W, h1b, h2W, h2b, out);
}